// Round 5
// baseline (762.671 us; speedup 1.0000x reference)
//
#include <hip/hip_runtime.h>
#include <cstdint>
#include <math.h>

#define B_SZ 512
#define K_SZ 1024
#define N_INTV 5
#define D_U 32
#define D_H 64
#define SEL_OUT (D_H * D_U + D_H + 1) /* 2113 */

#define KP 1056            /* logical K: 1024 quadratic + 32 linear */
#define KPL 1088           /* LDS row stride: [0,1024) quad | [1024,1056) tail | pad */
#define NTILES (B_SZ * K_SZ / 32)   /* 16384 tiles of 32 events */
#define P1_BLOCKS 256
#define P1_THREADS 1024    /* 16 waves */

typedef __attribute__((ext_vector_type(8))) short bf16x8;
typedef __attribute__((ext_vector_type(16))) float f32x16;
typedef __attribute__((ext_vector_type(2))) float f32x2;

__device__ inline uint16_t f2bf_rne(float f) {
    uint32_t u = __builtin_bit_cast(uint32_t, f);
    uint32_t r = (u + 0x7FFFu + ((u >> 16) & 1u)) >> 16;
    return (uint16_t)r;
}
// pack two fp32 -> bf16x2 dword by byte-perm truncation (1 VALU per pair)
__device__ inline uint32_t pack_bf16_trunc(float lo, float hi) {
    return __builtin_amdgcn_perm(__builtin_bit_cast(uint32_t, hi),
                                 __builtin_bit_cast(uint32_t, lo), 0x07060302u);
}
__device__ inline float rdlane(float v, int l) {
    return __builtin_bit_cast(float,
        (uint32_t)__builtin_amdgcn_readlane(__builtin_bit_cast(uint32_t, v), l));
}

// ---------------- Phase 1: 32x32x16 MFMA quadratic-form GEMM -------------
// Bu[e][h] = p(e) . W[h], p = [u (x) u (1024) | u (32)], K = 1056.
// LDS row stride 1088. Quadratic region swizzled elem^=(h&7)<<3 (closed in
// [0,1024)); 32-elem tail swizzled elem^=(h&3)<<3 (closed in [1024,1056)).
// NO inline asm anywhere (rule #18: asm reading MFMA accs risks hazard bugs).
__global__ __launch_bounds__(P1_THREADS) void im_phase1(
    const float* __restrict__ t_int, const float* __restrict__ U_int,
    const float* __restrict__ Wp, const float* __restrict__ bp,
    const float* __restrict__ gamma, const float* __restrict__ beta,
    const float* __restrict__ Bmat, const float* __restrict__ Ws,
    const float* __restrict__ bs,
    float* __restrict__ Bu, float* __restrict__ xbuf)
{
    extern __shared__ uint16_t Wl[];   // [64][KPL] bf16, swizzled
    const int tid = threadIdx.x;

    // ---- stage W (once per block) ----
    for (int idx = tid; idx < D_H * KP; idx += P1_THREADS) {
        int h = idx / KP;
        int k = idx - h * KP;
        float v;
        int dst;
        if (k < 1024) {
            int i = k >> 5, j = k & 31;
            v = Ws[(size_t)(h * D_U + i) * D_U + j];
            dst = k ^ ((h & 7) << 3);
        } else {
            int i = k - 1024;
            v = Bmat[h * D_U + i] + bs[h * D_U + i];
            dst = 1024 + (i ^ ((h & 3) << 3));
        }
        Wl[h * KPL + dst] = f2bf_rne(v);
    }
    __syncthreads();

    const int wid  = tid >> 6;
    const int lane = tid & 63;
    const int colr = lane & 31;   // event row (A) / h col (B)
    const int half = lane >> 5;   // k-octet selector
    const int xr   = (lane & 7) << 3;   // quad-region XOR (h&7 == lane&7)
    const int lowp = (8 * half) ^ (xr & 8);

    // quad-region LDS byte offsets: read step s (<64) at boff[nt][s&3] + (s>>2)*128
    uint32_t boff[2][4];
    #pragma unroll
    for (int nt = 0; nt < 2; ++nt)
        #pragma unroll
        for (int m = 0; m < 4; ++m)
            boff[nt][m] = 2u * (((nt * 32 + colr) * KPL) + lowp +
                                (((m ^ ((xr >> 4) & 3)) & 3) << 4));
    // tail LDS byte offsets (steps 64, 65): XOR confined to (h&3)<<3
    uint32_t toff[2][2];
    #pragma unroll
    for (int nt = 0; nt < 2; ++nt) {
        int e0 = 1024 + ((8 * half) ^ ((colr & 3) << 3));
        int e1 = 1024 + ((16 + 8 * half) ^ ((colr & 3) << 3));
        toff[nt][0] = 2u * ((nt * 32 + colr) * KPL + e0);
        toff[nt][1] = 2u * ((nt * 32 + colr) * KPL + e1);
    }

    for (int tile = blockIdx.x * 16 + wid; tile < NTILES; tile += P1_BLOCKS * 16) {
        const int base = tile << 5;
        const int ev   = base + colr;   // this lane's event (2x redundant across half)

        // ---- load U (5 feats), project 5->32, layernorm ----
        float Uin[N_INTV];
        #pragma unroll
        for (int c = 0; c < N_INTV; ++c)
            Uin[c] = U_int[(size_t)ev * N_INTV + c];

        float u[D_U];
        #pragma unroll
        for (int d = 0; d < D_U; ++d) {
            float acc = bp[d];
            #pragma unroll
            for (int c = 0; c < N_INTV; ++c)
                acc = fmaf(Wp[d * N_INTV + c], Uin[c], acc);
            u[d] = acc;
        }
        float mu = 0.f;
        #pragma unroll
        for (int d = 0; d < D_U; ++d) mu += u[d];
        mu *= (1.f / D_U);
        float m2 = 0.f;
        #pragma unroll
        for (int d = 0; d < D_U; ++d) { float t = u[d] - mu; m2 += t * t; }
        float rs = rsqrtf(m2 * (1.f / D_U) + 1e-5f);
        #pragma unroll
        for (int d = 0; d < D_U; ++d)
            u[d] = (u[d] - mu) * rs * gamma[d] + beta[d];

        // ---- xbuf (one lane per event) ----
        if (half == 0) {
            const float* wr = Ws + (size_t)(SEL_OUT - 1) * D_U;
            float s = bs[SEL_OUT - 1];
            #pragma unroll
            for (int j = 0; j < D_U; ++j) s = fmaf(wr[j], u[j], s);
            float sp = fmaxf(s, 0.f) + log1pf(expf(-fabsf(s)));
            int kk = ev & (K_SZ - 1);
            float dtv = 0.f;
            if (kk > 0) dtv = fmaxf(t_int[ev] - t_int[ev - 1], 0.f);
            xbuf[ev] = dtv * sp;
        }

        // ---- this lane's j-slices as f32x2 pairs (select on half) ----
        f32x2 v2[8];
        #pragma unroll
        for (int p = 0; p < 4; ++p) {
            f32x2 a0 = { u[2 * p],      u[2 * p + 1]      };
            f32x2 a1 = { u[8 + 2 * p],  u[9 + 2 * p]      };
            f32x2 b0 = { u[16 + 2 * p], u[17 + 2 * p]     };
            f32x2 b1 = { u[24 + 2 * p], u[25 + 2 * p]     };
            v2[p]     = half ? a1 : a0;   // even step slice: jj0 = 8*half
            v2[4 + p] = half ? b1 : b0;   // odd  step slice: jj0 = 16 + 8*half
        }

        f32x16 acc0, acc1;
        #pragma unroll
        for (int i = 0; i < 16; ++i) { acc0[i] = 0.f; acc1[i] = 0.f; }

        union AF { uint32_t w[4]; bf16x8 v; };

        // ---- 64 quadratic K-steps ----
        #pragma unroll
        for (int s = 0; s < 64; ++s) {
            float uts = u[s >> 1];
            f32x2 utv = { uts, uts };
            const int sl = (s & 1) * 4;
            AF af;
            f32x2 p0 = utv * v2[sl + 0];
            f32x2 p1 = utv * v2[sl + 1];
            f32x2 p2 = utv * v2[sl + 2];
            f32x2 p3 = utv * v2[sl + 3];
            af.w[0] = pack_bf16_trunc(p0.x, p0.y);
            af.w[1] = pack_bf16_trunc(p1.x, p1.y);
            af.w[2] = pack_bf16_trunc(p2.x, p2.y);
            af.w[3] = pack_bf16_trunc(p3.x, p3.y);
            bf16x8 b0 = *(const bf16x8*)((const char*)Wl + boff[0][s & 3] + (s >> 2) * 128);
            bf16x8 b1 = *(const bf16x8*)((const char*)Wl + boff[1][s & 3] + (s >> 2) * 128);
            acc0 = __builtin_amdgcn_mfma_f32_32x32x16_bf16(af.v, b0, acc0, 0, 0, 0);
            acc1 = __builtin_amdgcn_mfma_f32_32x32x16_bf16(af.v, b1, acc1, 0, 0, 0);
        }
        // ---- 2 linear tail steps (p = u) ----
        #pragma unroll
        for (int s = 0; s < 2; ++s) {
            const int sl = s * 4;
            AF af;
            af.w[0] = pack_bf16_trunc(v2[sl + 0].x, v2[sl + 0].y);
            af.w[1] = pack_bf16_trunc(v2[sl + 1].x, v2[sl + 1].y);
            af.w[2] = pack_bf16_trunc(v2[sl + 2].x, v2[sl + 2].y);
            af.w[3] = pack_bf16_trunc(v2[sl + 3].x, v2[sl + 3].y);
            bf16x8 b0 = *(const bf16x8*)((const char*)Wl + toff[0][s]);
            bf16x8 b1 = *(const bf16x8*)((const char*)Wl + toff[1][s]);
            acc0 = __builtin_amdgcn_mfma_f32_32x32x16_bf16(af.v, b0, acc0, 0, 0, 0);
            acc1 = __builtin_amdgcn_mfma_f32_32x32x16_bf16(af.v, b1, acc1, 0, 0, 0);
        }

        // ---- C store (plain f32, no asm): row(reg)=(reg&3)+8*(reg>>2)+4*half ----
        float* bo = Bu + (size_t)base * D_H;
        #pragma unroll
        for (int rg = 0; rg < 16; ++rg) {
            int r0 = (rg & 3) + 8 * (rg >> 2) + 4 * half;
            bo[(size_t)r0 * D_H + colr]      = acc0[rg];
            bo[(size_t)r0 * D_H + 32 + colr] = acc1[rg];
        }
    }
}

// ---------------- Phase 2: chunked scan, one block per batch row ----------
// 8 waves = 8 chunks of 128 steps. Pass 1: per-chunk affine (P,Q) with Bu
// (f32) packed to bf16 pairs parked in 64 VGPRs. Block scan via LDS. Pass 2:
// replay from regs.
#define NCH 8
#define CLEN 128
__global__ __launch_bounds__(512) void im_scan(
    const float* __restrict__ h0, const int* __restrict__ int_lens,
    const float* __restrict__ A_log,
    const float* __restrict__ Bu, const float* __restrict__ xbuf,
    float* __restrict__ out)
{
    __shared__ float Pl[NCH][64], Ql[NCH][64];
    const int b = blockIdx.x;
    const int wave = threadIdx.x >> 6;
    const int lane = threadIdx.x & 63;
    const int k0 = wave * CLEN;

    float A = -__expf(A_log[lane]);
    float invA = 1.f / A;
    int len = int_lens[b];

    float xv0 = xbuf[(size_t)b * K_SZ + k0 + lane];
    float xv1 = xbuf[(size_t)b * K_SZ + k0 + 64 + lane];
    const float* bup = Bu + ((size_t)(b * K_SZ + k0)) * D_H + lane;

    uint32_t bu[64];
    float P = 1.f, Q = 0.f;
    #pragma unroll
    for (int s2 = 0; s2 < 64; ++s2) {
        float lo = bup[(size_t)(2 * s2) * D_H];
        float hi = bup[(size_t)(2 * s2 + 1) * D_H];
        bu[s2] = pack_bf16_trunc(lo, hi);
        {
            const int t = 2 * s2;
            float x = (t < 64) ? rdlane(xv0, t & 63) : rdlane(xv1, t & 63);
            float eA = __expf(A * x);
            bool act = (k0 + t) < len;
            float Pf = act ? eA : 1.f;
            float cf = act ? (eA - 1.f) * invA * lo : 0.f;
            P *= Pf;
            Q = fmaf(Pf, Q, cf);
        }
        {
            const int t = 2 * s2 + 1;
            float x = (t < 64) ? rdlane(xv0, t & 63) : rdlane(xv1, t & 63);
            float eA = __expf(A * x);
            bool act = (k0 + t) < len;
            float Pf = act ? eA : 1.f;
            float cf = act ? (eA - 1.f) * invA * hi : 0.f;
            P *= Pf;
            Q = fmaf(Pf, Q, cf);
        }
    }
    Pl[wave][lane] = P;
    Ql[wave][lane] = Q;
    __syncthreads();

    // chunk start state
    float hv = h0[b * D_H + lane];
    for (int cc = 0; cc < wave; ++cc)
        hv = fmaf(Pl[cc][lane], hv, Ql[cc][lane]);

    float* times  = out + (size_t)B_SZ * D_H;
    float* states = times + (size_t)(K_SZ + 1) * B_SZ;
    if (wave == 0)
        states[(size_t)b * D_H + lane] = hv;   // states[0] = h0

    // replay from registers (Bu truncated to bf16 in-reg; error ~0.8% rel max)
    #pragma unroll
    for (int s2 = 0; s2 < 64; ++s2) {
        uint32_t w = bu[s2];
        {
            const int t = 2 * s2;
            float Buf = __builtin_bit_cast(float, w << 16);
            float x = (t < 64) ? rdlane(xv0, t & 63) : rdlane(xv1, t & 63);
            float eA = __expf(A * x);
            float hn = fmaf(eA, hv, (eA - 1.f) * invA * Buf);
            hv = ((k0 + t) < len) ? hn : hv;
            states[((size_t)(k0 + t + 1) * B_SZ + b) * D_H + lane] = hv;
        }
        {
            const int t = 2 * s2 + 1;
            float Buf = __builtin_bit_cast(float, w & 0xFFFF0000u);
            float x = (t < 64) ? rdlane(xv0, t & 63) : rdlane(xv1, t & 63);
            float eA = __expf(A * x);
            float hn = fmaf(eA, hv, (eA - 1.f) * invA * Buf);
            hv = ((k0 + t) < len) ? hn : hv;
            states[((size_t)(k0 + t + 1) * B_SZ + b) * D_H + lane] = hv;
        }
    }
    if (wave == NCH - 1)
        out[b * D_H + lane] = hv;   // h_final
}

// ---------------- times: (K+1, B) transpose of t_int ----------------------
__global__ __launch_bounds__(256) void im_times(
    const float* __restrict__ t_int, float* __restrict__ out)
{
    int idx = blockIdx.x * blockDim.x + threadIdx.x;
    if (idx >= (K_SZ + 1) * B_SZ) return;
    int kp = idx >> 9;            // / B_SZ
    int b  = idx & (B_SZ - 1);
    int ks = (kp == 0) ? 0 : kp - 1;
    float* times = out + (size_t)B_SZ * D_H;
    times[idx] = t_int[(size_t)b * K_SZ + ks];
}

extern "C" void kernel_launch(void* const* d_in, const int* in_sizes, int n_in,
                              void* d_out, int out_size, void* d_ws, size_t ws_size,
                              hipStream_t stream) {
    const float* h0       = (const float*)d_in[0];
    const float* t_int    = (const float*)d_in[1];
    const float* U_int    = (const float*)d_in[2];
    const int*   int_lens = (const int*)d_in[3];
    const float* Wp       = (const float*)d_in[4];
    const float* bp       = (const float*)d_in[5];
    const float* gamma    = (const float*)d_in[6];
    const float* beta     = (const float*)d_in[7];
    const float* A_log    = (const float*)d_in[8];
    const float* Bmat     = (const float*)d_in[9];
    const float* Ws       = (const float*)d_in[10];
    const float* bs       = (const float*)d_in[11];

    float* out = (float*)d_out;
    float* Bu   = (float*)d_ws;                                    // B*K*D_H f32
    float* xbuf = (float*)((char*)d_ws + (size_t)B_SZ * K_SZ * D_H * sizeof(float));

    size_t lds_bytes = (size_t)D_H * KPL * sizeof(uint16_t);   // 139264
    im_phase1<<<dim3(P1_BLOCKS), dim3(P1_THREADS), lds_bytes, stream>>>(
        t_int, U_int, Wp, bp, gamma, beta, Bmat, Ws, bs, Bu, xbuf);

    im_times<<<dim3(((K_SZ + 1) * B_SZ + 255) / 256), dim3(256), 0, stream>>>(t_int, out);

    im_scan<<<dim3(B_SZ), dim3(512), 0, stream>>>(h0, int_lens, A_log, Bu, xbuf, out);
}

// Round 6
// 694.092 us; speedup vs baseline: 1.0988x; 1.0988x over previous
//
#include <hip/hip_runtime.h>
#include <cstdint>
#include <math.h>

#define B_SZ 512
#define K_SZ 1024
#define N_INTV 5
#define D_U 32
#define D_H 64
#define SEL_OUT (D_H * D_U + D_H + 1) /* 2113 */

#define KP 1056            /* logical K: 1024 quadratic + 32 linear */
#define KPL 1088           /* LDS row stride: [0,1024) quad | [1024,1056) tail | pad */
#define NTILES (B_SZ * K_SZ / 32)   /* 16384 tiles of 32 events */
#define P1_BLOCKS 256
#define P1_THREADS 512     /* 8 waves: 2/SIMD -> 256-VGPR budget, no spill */

typedef __attribute__((ext_vector_type(8))) short bf16x8;
typedef __attribute__((ext_vector_type(16))) float f32x16;
typedef __attribute__((ext_vector_type(2))) float f32x2;

__device__ inline uint16_t f2bf_rne(float f) {
    uint32_t u = __builtin_bit_cast(uint32_t, f);
    uint32_t r = (u + 0x7FFFu + ((u >> 16) & 1u)) >> 16;
    return (uint16_t)r;
}
// pack two fp32 -> bf16x2 dword by byte-perm truncation (1 VALU per pair)
__device__ inline uint32_t pack_bf16_trunc(float lo, float hi) {
    return __builtin_amdgcn_perm(__builtin_bit_cast(uint32_t, hi),
                                 __builtin_bit_cast(uint32_t, lo), 0x07060302u);
}
__device__ inline float rdlane(float v, int l) {
    return __builtin_bit_cast(float,
        (uint32_t)__builtin_amdgcn_readlane(__builtin_bit_cast(uint32_t, v), l));
}

// ---------------- Phase 1: 32x32x16 MFMA quadratic-form GEMM -------------
// Bu[e][h] = p(e) . W[h], p = [u (x) u (1024) | u (32)], K = 1056.
// LDS row stride 1088. Quadratic region swizzled elem^=(h&7)<<3 (closed in
// [0,1024)); 32-elem tail swizzled elem^=(h&3)<<3 (closed in [1024,1056)).
__global__ __launch_bounds__(P1_THREADS) void im_phase1(
    const float* __restrict__ t_int, const float* __restrict__ U_int,
    const float* __restrict__ Wp, const float* __restrict__ bp,
    const float* __restrict__ gamma, const float* __restrict__ beta,
    const float* __restrict__ Bmat, const float* __restrict__ Ws,
    const float* __restrict__ bs,
    float* __restrict__ Bu, float* __restrict__ xbuf)
{
    extern __shared__ uint16_t Wl[];   // [64][KPL] bf16, swizzled
    const int tid = threadIdx.x;

    // ---- stage W (once per block) ----
    for (int idx = tid; idx < D_H * KP; idx += P1_THREADS) {
        int h = idx / KP;
        int k = idx - h * KP;
        float v;
        int dst;
        if (k < 1024) {
            int i = k >> 5, j = k & 31;
            v = Ws[(size_t)(h * D_U + i) * D_U + j];
            dst = k ^ ((h & 7) << 3);
        } else {
            int i = k - 1024;
            v = Bmat[h * D_U + i] + bs[h * D_U + i];
            dst = 1024 + (i ^ ((h & 3) << 3));
        }
        Wl[h * KPL + dst] = f2bf_rne(v);
    }
    __syncthreads();

    const int wid  = tid >> 6;
    const int lane = tid & 63;
    const int colr = lane & 31;   // event row (A) / h col (B)
    const int half = lane >> 5;   // k-octet selector
    const int xr   = (lane & 7) << 3;   // quad-region XOR (h&7 == lane&7)
    const int lowp = (8 * half) ^ (xr & 8);

    // quad-region LDS byte offsets: read step s (<64) at boff[nt][s&3] + (s>>2)*128
    uint32_t boff[2][4];
    #pragma unroll
    for (int nt = 0; nt < 2; ++nt)
        #pragma unroll
        for (int m = 0; m < 4; ++m)
            boff[nt][m] = 2u * (((nt * 32 + colr) * KPL) + lowp +
                                (((m ^ ((xr >> 4) & 3)) & 3) << 4));
    // tail LDS byte offsets (steps 64, 65): XOR confined to (h&3)<<3
    uint32_t toff[2][2];
    #pragma unroll
    for (int nt = 0; nt < 2; ++nt) {
        int e0 = 1024 + ((8 * half) ^ ((colr & 3) << 3));
        int e1 = 1024 + ((16 + 8 * half) ^ ((colr & 3) << 3));
        toff[nt][0] = 2u * ((nt * 32 + colr) * KPL + e0);
        toff[nt][1] = 2u * ((nt * 32 + colr) * KPL + e1);
    }

    for (int tile = blockIdx.x * 8 + wid; tile < NTILES; tile += P1_BLOCKS * 8) {
        const int base = tile << 5;
        const int ev   = base + colr;   // this lane's event (2x redundant across half)

        // ---- load U (5 feats), project 5->32, layernorm ----
        float Uin[N_INTV];
        #pragma unroll
        for (int c = 0; c < N_INTV; ++c)
            Uin[c] = U_int[(size_t)ev * N_INTV + c];

        float u[D_U];
        #pragma unroll
        for (int d = 0; d < D_U; ++d) {
            float acc = bp[d];
            #pragma unroll
            for (int c = 0; c < N_INTV; ++c)
                acc = fmaf(Wp[d * N_INTV + c], Uin[c], acc);
            u[d] = acc;
        }
        float mu = 0.f;
        #pragma unroll
        for (int d = 0; d < D_U; ++d) mu += u[d];
        mu *= (1.f / D_U);
        float m2 = 0.f;
        #pragma unroll
        for (int d = 0; d < D_U; ++d) { float t = u[d] - mu; m2 += t * t; }
        float rs = rsqrtf(m2 * (1.f / D_U) + 1e-5f);
        #pragma unroll
        for (int d = 0; d < D_U; ++d)
            u[d] = (u[d] - mu) * rs * gamma[d] + beta[d];

        // ---- xbuf (one lane per event) ----
        if (half == 0) {
            const float* wr = Ws + (size_t)(SEL_OUT - 1) * D_U;
            float s = bs[SEL_OUT - 1];
            #pragma unroll
            for (int j = 0; j < D_U; ++j) s = fmaf(wr[j], u[j], s);
            float sp = fmaxf(s, 0.f) + log1pf(expf(-fabsf(s)));
            int kk = ev & (K_SZ - 1);
            float dtv = 0.f;
            if (kk > 0) dtv = fmaxf(t_int[ev] - t_int[ev - 1], 0.f);
            xbuf[ev] = dtv * sp;
        }

        // ---- this lane's j-slices as f32x2 pairs (select on half) ----
        f32x2 v2[8];
        #pragma unroll
        for (int p = 0; p < 4; ++p) {
            f32x2 a0 = { u[2 * p],      u[2 * p + 1]      };
            f32x2 a1 = { u[8 + 2 * p],  u[9 + 2 * p]      };
            f32x2 b0 = { u[16 + 2 * p], u[17 + 2 * p]     };
            f32x2 b1 = { u[24 + 2 * p], u[25 + 2 * p]     };
            v2[p]     = half ? a1 : a0;   // even step slice: jj0 = 8*half
            v2[4 + p] = half ? b1 : b0;   // odd  step slice: jj0 = 16 + 8*half
        }

        f32x16 acc0, acc1;
        #pragma unroll
        for (int i = 0; i < 16; ++i) { acc0[i] = 0.f; acc1[i] = 0.f; }

        union AF { uint32_t w[4]; bf16x8 v; };

        // ---- 64 quadratic K-steps ----
        #pragma unroll
        for (int s = 0; s < 64; ++s) {
            float uts = u[s >> 1];
            f32x2 utv = { uts, uts };
            const int sl = (s & 1) * 4;
            AF af;
            f32x2 p0 = utv * v2[sl + 0];
            f32x2 p1 = utv * v2[sl + 1];
            f32x2 p2 = utv * v2[sl + 2];
            f32x2 p3 = utv * v2[sl + 3];
            af.w[0] = pack_bf16_trunc(p0.x, p0.y);
            af.w[1] = pack_bf16_trunc(p1.x, p1.y);
            af.w[2] = pack_bf16_trunc(p2.x, p2.y);
            af.w[3] = pack_bf16_trunc(p3.x, p3.y);
            bf16x8 b0 = *(const bf16x8*)((const char*)Wl + boff[0][s & 3] + (s >> 2) * 128);
            bf16x8 b1 = *(const bf16x8*)((const char*)Wl + boff[1][s & 3] + (s >> 2) * 128);
            acc0 = __builtin_amdgcn_mfma_f32_32x32x16_bf16(af.v, b0, acc0, 0, 0, 0);
            acc1 = __builtin_amdgcn_mfma_f32_32x32x16_bf16(af.v, b1, acc1, 0, 0, 0);
        }
        // ---- 2 linear tail steps (p = u) ----
        #pragma unroll
        for (int s = 0; s < 2; ++s) {
            const int sl = s * 4;
            AF af;
            af.w[0] = pack_bf16_trunc(v2[sl + 0].x, v2[sl + 0].y);
            af.w[1] = pack_bf16_trunc(v2[sl + 1].x, v2[sl + 1].y);
            af.w[2] = pack_bf16_trunc(v2[sl + 2].x, v2[sl + 2].y);
            af.w[3] = pack_bf16_trunc(v2[sl + 3].x, v2[sl + 3].y);
            bf16x8 b0 = *(const bf16x8*)((const char*)Wl + toff[0][s]);
            bf16x8 b1 = *(const bf16x8*)((const char*)Wl + toff[1][s]);
            acc0 = __builtin_amdgcn_mfma_f32_32x32x16_bf16(af.v, b0, acc0, 0, 0, 0);
            acc1 = __builtin_amdgcn_mfma_f32_32x32x16_bf16(af.v, b1, acc1, 0, 0, 0);
        }

        // ---- C store (plain f32): row(reg)=(reg&3)+8*(reg>>2)+4*half ----
        float* bo = Bu + (size_t)base * D_H;
        #pragma unroll
        for (int rg = 0; rg < 16; ++rg) {
            int r0 = (rg & 3) + 8 * (rg >> 2) + 4 * half;
            bo[(size_t)r0 * D_H + colr]      = acc0[rg];
            bo[(size_t)r0 * D_H + 32 + colr] = acc1[rg];
        }
    }
}

// ---------------- Phase 2: chunked scan, one block per batch row ----------
// 8 waves = 8 chunks of 128 steps. Pass 1: per-chunk affine (P,Q) with Bu
// (f32) packed to bf16 pairs parked in 64 VGPRs. Block scan via LDS. Pass 2:
// replay from regs.
#define NCH 8
#define CLEN 128
__global__ __launch_bounds__(512) void im_scan(
    const float* __restrict__ h0, const int* __restrict__ int_lens,
    const float* __restrict__ A_log,
    const float* __restrict__ Bu, const float* __restrict__ xbuf,
    float* __restrict__ out)
{
    __shared__ float Pl[NCH][64], Ql[NCH][64];
    const int b = blockIdx.x;
    const int wave = threadIdx.x >> 6;
    const int lane = threadIdx.x & 63;
    const int k0 = wave * CLEN;

    float A = -__expf(A_log[lane]);
    float invA = 1.f / A;
    int len = int_lens[b];

    float xv0 = xbuf[(size_t)b * K_SZ + k0 + lane];
    float xv1 = xbuf[(size_t)b * K_SZ + k0 + 64 + lane];
    const float* bup = Bu + ((size_t)(b * K_SZ + k0)) * D_H + lane;

    uint32_t bu[64];
    float P = 1.f, Q = 0.f;
    #pragma unroll
    for (int s2 = 0; s2 < 64; ++s2) {
        float lo = bup[(size_t)(2 * s2) * D_H];
        float hi = bup[(size_t)(2 * s2 + 1) * D_H];
        bu[s2] = pack_bf16_trunc(lo, hi);
        {
            const int t = 2 * s2;
            float x = (t < 64) ? rdlane(xv0, t & 63) : rdlane(xv1, t & 63);
            float eA = __expf(A * x);
            bool act = (k0 + t) < len;
            float Pf = act ? eA : 1.f;
            float cf = act ? (eA - 1.f) * invA * lo : 0.f;
            P *= Pf;
            Q = fmaf(Pf, Q, cf);
        }
        {
            const int t = 2 * s2 + 1;
            float x = (t < 64) ? rdlane(xv0, t & 63) : rdlane(xv1, t & 63);
            float eA = __expf(A * x);
            bool act = (k0 + t) < len;
            float Pf = act ? eA : 1.f;
            float cf = act ? (eA - 1.f) * invA * hi : 0.f;
            P *= Pf;
            Q = fmaf(Pf, Q, cf);
        }
    }
    Pl[wave][lane] = P;
    Ql[wave][lane] = Q;
    __syncthreads();

    // chunk start state
    float hv = h0[b * D_H + lane];
    for (int cc = 0; cc < wave; ++cc)
        hv = fmaf(Pl[cc][lane], hv, Ql[cc][lane]);

    float* times  = out + (size_t)B_SZ * D_H;
    float* states = times + (size_t)(K_SZ + 1) * B_SZ;
    if (wave == 0)
        states[(size_t)b * D_H + lane] = hv;   // states[0] = h0

    // replay from registers (Bu truncated to bf16 in-reg)
    #pragma unroll
    for (int s2 = 0; s2 < 64; ++s2) {
        uint32_t w = bu[s2];
        {
            const int t = 2 * s2;
            float Buf = __builtin_bit_cast(float, w << 16);
            float x = (t < 64) ? rdlane(xv0, t & 63) : rdlane(xv1, t & 63);
            float eA = __expf(A * x);
            float hn = fmaf(eA, hv, (eA - 1.f) * invA * Buf);
            hv = ((k0 + t) < len) ? hn : hv;
            states[((size_t)(k0 + t + 1) * B_SZ + b) * D_H + lane] = hv;
        }
        {
            const int t = 2 * s2 + 1;
            float Buf = __builtin_bit_cast(float, w & 0xFFFF0000u);
            float x = (t < 64) ? rdlane(xv0, t & 63) : rdlane(xv1, t & 63);
            float eA = __expf(A * x);
            float hn = fmaf(eA, hv, (eA - 1.f) * invA * Buf);
            hv = ((k0 + t) < len) ? hn : hv;
            states[((size_t)(k0 + t + 1) * B_SZ + b) * D_H + lane] = hv;
        }
    }
    if (wave == NCH - 1)
        out[b * D_H + lane] = hv;   // h_final
}

// ---------------- times: (K+1, B) transpose of t_int ----------------------
__global__ __launch_bounds__(256) void im_times(
    const float* __restrict__ t_int, float* __restrict__ out)
{
    int idx = blockIdx.x * blockDim.x + threadIdx.x;
    if (idx >= (K_SZ + 1) * B_SZ) return;
    int kp = idx >> 9;            // / B_SZ
    int b  = idx & (B_SZ - 1);
    int ks = (kp == 0) ? 0 : kp - 1;
    float* times = out + (size_t)B_SZ * D_H;
    times[idx] = t_int[(size_t)b * K_SZ + ks];
}

extern "C" void kernel_launch(void* const* d_in, const int* in_sizes, int n_in,
                              void* d_out, int out_size, void* d_ws, size_t ws_size,
                              hipStream_t stream) {
    const float* h0       = (const float*)d_in[0];
    const float* t_int    = (const float*)d_in[1];
    const float* U_int    = (const float*)d_in[2];
    const int*   int_lens = (const int*)d_in[3];
    const float* Wp       = (const float*)d_in[4];
    const float* bp       = (const float*)d_in[5];
    const float* gamma    = (const float*)d_in[6];
    const float* beta     = (const float*)d_in[7];
    const float* A_log    = (const float*)d_in[8];
    const float* Bmat     = (const float*)d_in[9];
    const float* Ws       = (const float*)d_in[10];
    const float* bs       = (const float*)d_in[11];

    float* out = (float*)d_out;
    float* Bu   = (float*)d_ws;                                    // B*K*D_H f32
    float* xbuf = (float*)((char*)d_ws + (size_t)B_SZ * K_SZ * D_H * sizeof(float));

    size_t lds_bytes = (size_t)D_H * KPL * sizeof(uint16_t);   // 139264
    im_phase1<<<dim3(P1_BLOCKS), dim3(P1_THREADS), lds_bytes, stream>>>(
        t_int, U_int, Wp, bp, gamma, beta, Bmat, Ws, bs, Bu, xbuf);

    im_times<<<dim3(((K_SZ + 1) * B_SZ + 255) / 256), dim3(256), 0, stream>>>(t_int, out);

    im_scan<<<dim3(B_SZ), dim3(512), 0, stream>>>(h0, int_lens, A_log, Bu, xbuf, out);
}

// Round 7
// 688.177 us; speedup vs baseline: 1.1082x; 1.0086x over previous
//
#include <hip/hip_runtime.h>
#include <cstdint>
#include <math.h>

#define B_SZ 512
#define K_SZ 1024
#define N_INTV 5
#define D_U 32
#define D_H 64
#define SEL_OUT (D_H * D_U + D_H + 1) /* 2113 */

#define KP 1056            /* logical K: 1024 quadratic + 32 linear */
#define KPL 1088           /* LDS row stride: [0,1024) quad | [1024,1056) tail | pad */
#define NTILES (B_SZ * K_SZ / 32)   /* 16384 tiles of 32 events */
#define P1_BLOCKS 256
#define P1_THREADS 512     /* 8 waves */

typedef __attribute__((ext_vector_type(8))) short bf16x8;
typedef __attribute__((ext_vector_type(16))) float f32x16;
typedef __attribute__((ext_vector_type(2))) float f32x2;

__device__ inline uint16_t f2bf_rne(float f) {
    uint32_t u = __builtin_bit_cast(uint32_t, f);
    uint32_t r = (u + 0x7FFFu + ((u >> 16) & 1u)) >> 16;
    return (uint16_t)r;
}
// pack two fp32 -> bf16x2 dword by byte-perm truncation (1 VALU per pair)
__device__ inline uint32_t pack_bf16_trunc(float lo, float hi) {
    return __builtin_amdgcn_perm(__builtin_bit_cast(uint32_t, hi),
                                 __builtin_bit_cast(uint32_t, lo), 0x07060302u);
}
__device__ inline float rdlane(float v, int l) {
    return __builtin_bit_cast(float,
        (uint32_t)__builtin_amdgcn_readlane(__builtin_bit_cast(uint32_t, v), l));
}

// ---------------- Phase 1: 32x32x16 MFMA quadratic-form GEMM -------------
// Bu[e][h] = p(e) . W[h], p = [u (x) u (1024) | u (32)], K = 1056.
// LDS row stride 1088. Quadratic region swizzled elem^=(h&7)<<3 (closed in
// [0,1024)); 32-elem tail swizzled elem^=(h&3)<<3 (closed in [1024,1056)).
// __launch_bounds__(512, 2): LDS caps us at 1 block/CU (2 waves/SIMD) anyway;
// declaring it lifts the VGPR cap to 256 -> no scratch spill (R6 lesson).
__global__ __launch_bounds__(P1_THREADS, 2) void im_phase1(
    const float* __restrict__ t_int, const float* __restrict__ U_int,
    const float* __restrict__ Wp, const float* __restrict__ bp,
    const float* __restrict__ gamma, const float* __restrict__ beta,
    const float* __restrict__ Bmat, const float* __restrict__ Ws,
    const float* __restrict__ bs,
    float* __restrict__ Bu, float* __restrict__ xbuf)
{
    extern __shared__ uint16_t Wl[];   // [64][KPL] bf16, swizzled
    const int tid = threadIdx.x;

    // ---- stage W (once per block) ----
    for (int idx = tid; idx < D_H * KP; idx += P1_THREADS) {
        int h = idx / KP;
        int k = idx - h * KP;
        float v;
        int dst;
        if (k < 1024) {
            int i = k >> 5, j = k & 31;
            v = Ws[(size_t)(h * D_U + i) * D_U + j];
            dst = k ^ ((h & 7) << 3);
        } else {
            int i = k - 1024;
            v = Bmat[h * D_U + i] + bs[h * D_U + i];
            dst = 1024 + (i ^ ((h & 3) << 3));
        }
        Wl[h * KPL + dst] = f2bf_rne(v);
    }
    __syncthreads();

    const int wid  = tid >> 6;
    const int lane = tid & 63;
    const int colr = lane & 31;   // event row (A) / h col (B)
    const int half = lane >> 5;   // k-octet selector
    const int xr   = (lane & 7) << 3;   // quad-region XOR (h&7 == lane&7)
    const int lowp = (8 * half) ^ (xr & 8);

    // quad-region LDS byte offsets: read step s (<64) at boff[nt][s&3] + (s>>2)*128
    uint32_t boff[2][4];
    #pragma unroll
    for (int nt = 0; nt < 2; ++nt)
        #pragma unroll
        for (int m = 0; m < 4; ++m)
            boff[nt][m] = 2u * (((nt * 32 + colr) * KPL) + lowp +
                                (((m ^ ((xr >> 4) & 3)) & 3) << 4));
    // tail LDS byte offsets (steps 64, 65): XOR confined to (h&3)<<3
    uint32_t toff[2][2];
    #pragma unroll
    for (int nt = 0; nt < 2; ++nt) {
        int e0 = 1024 + ((8 * half) ^ ((colr & 3) << 3));
        int e1 = 1024 + ((16 + 8 * half) ^ ((colr & 3) << 3));
        toff[nt][0] = 2u * ((nt * 32 + colr) * KPL + e0);
        toff[nt][1] = 2u * ((nt * 32 + colr) * KPL + e1);
    }

    for (int tile = blockIdx.x * 8 + wid; tile < NTILES; tile += P1_BLOCKS * 8) {
        const int base = tile << 5;
        const int ev   = base + colr;   // this lane's event (2x redundant across half)

        // ---- load U (5 feats), project 5->32, layernorm ----
        float Uin[N_INTV];
        #pragma unroll
        for (int c = 0; c < N_INTV; ++c)
            Uin[c] = U_int[(size_t)ev * N_INTV + c];

        float u[D_U];
        #pragma unroll
        for (int d = 0; d < D_U; ++d) {
            float acc = bp[d];
            #pragma unroll
            for (int c = 0; c < N_INTV; ++c)
                acc = fmaf(Wp[d * N_INTV + c], Uin[c], acc);
            u[d] = acc;
        }
        float mu = 0.f;
        #pragma unroll
        for (int d = 0; d < D_U; ++d) mu += u[d];
        mu *= (1.f / D_U);
        float m2 = 0.f;
        #pragma unroll
        for (int d = 0; d < D_U; ++d) { float t = u[d] - mu; m2 += t * t; }
        float rs = rsqrtf(m2 * (1.f / D_U) + 1e-5f);
        #pragma unroll
        for (int d = 0; d < D_U; ++d)
            u[d] = (u[d] - mu) * rs * gamma[d] + beta[d];

        // ---- xbuf (one lane per event) ----
        if (half == 0) {
            const float* wr = Ws + (size_t)(SEL_OUT - 1) * D_U;
            float s = bs[SEL_OUT - 1];
            #pragma unroll
            for (int j = 0; j < D_U; ++j) s = fmaf(wr[j], u[j], s);
            float sp = fmaxf(s, 0.f) + log1pf(expf(-fabsf(s)));
            int kk = ev & (K_SZ - 1);
            float dtv = 0.f;
            if (kk > 0) dtv = fmaxf(t_int[ev] - t_int[ev - 1], 0.f);
            xbuf[ev] = dtv * sp;
        }

        // ---- this lane's j-slices as f32x2 pairs (select on half) ----
        f32x2 v2[8];
        #pragma unroll
        for (int p = 0; p < 4; ++p) {
            f32x2 a0 = { u[2 * p],      u[2 * p + 1]      };
            f32x2 a1 = { u[8 + 2 * p],  u[9 + 2 * p]      };
            f32x2 b0 = { u[16 + 2 * p], u[17 + 2 * p]     };
            f32x2 b1 = { u[24 + 2 * p], u[25 + 2 * p]     };
            v2[p]     = half ? a1 : a0;   // even step slice: jj0 = 8*half
            v2[4 + p] = half ? b1 : b0;   // odd  step slice: jj0 = 16 + 8*half
        }

        f32x16 acc0, acc1;
        #pragma unroll
        for (int i = 0; i < 16; ++i) { acc0[i] = 0.f; acc1[i] = 0.f; }

        union AF { uint32_t w[4]; bf16x8 v; };

        // ---- 64 quadratic K-steps ----
        #pragma unroll
        for (int s = 0; s < 64; ++s) {
            float uts = u[s >> 1];
            f32x2 utv = { uts, uts };
            const int sl = (s & 1) * 4;
            AF af;
            f32x2 p0 = utv * v2[sl + 0];
            f32x2 p1 = utv * v2[sl + 1];
            f32x2 p2 = utv * v2[sl + 2];
            f32x2 p3 = utv * v2[sl + 3];
            af.w[0] = pack_bf16_trunc(p0.x, p0.y);
            af.w[1] = pack_bf16_trunc(p1.x, p1.y);
            af.w[2] = pack_bf16_trunc(p2.x, p2.y);
            af.w[3] = pack_bf16_trunc(p3.x, p3.y);
            bf16x8 b0 = *(const bf16x8*)((const char*)Wl + boff[0][s & 3] + (s >> 2) * 128);
            bf16x8 b1 = *(const bf16x8*)((const char*)Wl + boff[1][s & 3] + (s >> 2) * 128);
            acc0 = __builtin_amdgcn_mfma_f32_32x32x16_bf16(af.v, b0, acc0, 0, 0, 0);
            acc1 = __builtin_amdgcn_mfma_f32_32x32x16_bf16(af.v, b1, acc1, 0, 0, 0);
        }
        // ---- 2 linear tail steps (p = u) ----
        #pragma unroll
        for (int s = 0; s < 2; ++s) {
            const int sl = s * 4;
            AF af;
            af.w[0] = pack_bf16_trunc(v2[sl + 0].x, v2[sl + 0].y);
            af.w[1] = pack_bf16_trunc(v2[sl + 1].x, v2[sl + 1].y);
            af.w[2] = pack_bf16_trunc(v2[sl + 2].x, v2[sl + 2].y);
            af.w[3] = pack_bf16_trunc(v2[sl + 3].x, v2[sl + 3].y);
            bf16x8 b0 = *(const bf16x8*)((const char*)Wl + toff[0][s]);
            bf16x8 b1 = *(const bf16x8*)((const char*)Wl + toff[1][s]);
            acc0 = __builtin_amdgcn_mfma_f32_32x32x16_bf16(af.v, b0, acc0, 0, 0, 0);
            acc1 = __builtin_amdgcn_mfma_f32_32x32x16_bf16(af.v, b1, acc1, 0, 0, 0);
        }

        // ---- C store (plain f32): row(reg)=(reg&3)+8*(reg>>2)+4*half ----
        float* bo = Bu + (size_t)base * D_H;
        #pragma unroll
        for (int rg = 0; rg < 16; ++rg) {
            int r0 = (rg & 3) + 8 * (rg >> 2) + 4 * half;
            bo[(size_t)r0 * D_H + colr]      = acc0[rg];
            bo[(size_t)r0 * D_H + 32 + colr] = acc1[rg];
        }
    }
}

// ---------------- Phase 2: chunked scan, one block per batch row ----------
// 8 waves = 8 chunks of 128 steps. Pass 1: per-chunk affine (P,Q) with Bu
// (f32) packed to bf16 pairs parked in 64 VGPRs. Block scan via LDS. Pass 2:
// replay from regs.
#define NCH 8
#define CLEN 128
__global__ __launch_bounds__(512) void im_scan(
    const float* __restrict__ h0, const int* __restrict__ int_lens,
    const float* __restrict__ A_log,
    const float* __restrict__ Bu, const float* __restrict__ xbuf,
    float* __restrict__ out)
{
    __shared__ float Pl[NCH][64], Ql[NCH][64];
    const int b = blockIdx.x;
    const int wave = threadIdx.x >> 6;
    const int lane = threadIdx.x & 63;
    const int k0 = wave * CLEN;

    float A = -__expf(A_log[lane]);
    float invA = 1.f / A;
    int len = int_lens[b];

    float xv0 = xbuf[(size_t)b * K_SZ + k0 + lane];
    float xv1 = xbuf[(size_t)b * K_SZ + k0 + 64 + lane];
    const float* bup = Bu + ((size_t)(b * K_SZ + k0)) * D_H + lane;

    uint32_t bu[64];
    float P = 1.f, Q = 0.f;
    #pragma unroll
    for (int s2 = 0; s2 < 64; ++s2) {
        float lo = bup[(size_t)(2 * s2) * D_H];
        float hi = bup[(size_t)(2 * s2 + 1) * D_H];
        bu[s2] = pack_bf16_trunc(lo, hi);
        {
            const int t = 2 * s2;
            float x = (t < 64) ? rdlane(xv0, t & 63) : rdlane(xv1, t & 63);
            float eA = __expf(A * x);
            bool act = (k0 + t) < len;
            float Pf = act ? eA : 1.f;
            float cf = act ? (eA - 1.f) * invA * lo : 0.f;
            P *= Pf;
            Q = fmaf(Pf, Q, cf);
        }
        {
            const int t = 2 * s2 + 1;
            float x = (t < 64) ? rdlane(xv0, t & 63) : rdlane(xv1, t & 63);
            float eA = __expf(A * x);
            bool act = (k0 + t) < len;
            float Pf = act ? eA : 1.f;
            float cf = act ? (eA - 1.f) * invA * hi : 0.f;
            P *= Pf;
            Q = fmaf(Pf, Q, cf);
        }
    }
    Pl[wave][lane] = P;
    Ql[wave][lane] = Q;
    __syncthreads();

    // chunk start state
    float hv = h0[b * D_H + lane];
    for (int cc = 0; cc < wave; ++cc)
        hv = fmaf(Pl[cc][lane], hv, Ql[cc][lane]);

    float* times  = out + (size_t)B_SZ * D_H;
    float* states = times + (size_t)(K_SZ + 1) * B_SZ;
    if (wave == 0)
        states[(size_t)b * D_H + lane] = hv;   // states[0] = h0

    // replay from registers (Bu truncated to bf16 in-reg)
    #pragma unroll
    for (int s2 = 0; s2 < 64; ++s2) {
        uint32_t w = bu[s2];
        {
            const int t = 2 * s2;
            float Buf = __builtin_bit_cast(float, w << 16);
            float x = (t < 64) ? rdlane(xv0, t & 63) : rdlane(xv1, t & 63);
            float eA = __expf(A * x);
            float hn = fmaf(eA, hv, (eA - 1.f) * invA * Buf);
            hv = ((k0 + t) < len) ? hn : hv;
            states[((size_t)(k0 + t + 1) * B_SZ + b) * D_H + lane] = hv;
        }
        {
            const int t = 2 * s2 + 1;
            float Buf = __builtin_bit_cast(float, w & 0xFFFF0000u);
            float x = (t < 64) ? rdlane(xv0, t & 63) : rdlane(xv1, t & 63);
            float eA = __expf(A * x);
            float hn = fmaf(eA, hv, (eA - 1.f) * invA * Buf);
            hv = ((k0 + t) < len) ? hn : hv;
            states[((size_t)(k0 + t + 1) * B_SZ + b) * D_H + lane] = hv;
        }
    }
    if (wave == NCH - 1)
        out[b * D_H + lane] = hv;   // h_final
}

// ---------------- times: (K+1, B) transpose of t_int ----------------------
__global__ __launch_bounds__(256) void im_times(
    const float* __restrict__ t_int, float* __restrict__ out)
{
    int idx = blockIdx.x * blockDim.x + threadIdx.x;
    if (idx >= (K_SZ + 1) * B_SZ) return;
    int kp = idx >> 9;            // / B_SZ
    int b  = idx & (B_SZ - 1);
    int ks = (kp == 0) ? 0 : kp - 1;
    float* times = out + (size_t)B_SZ * D_H;
    times[idx] = t_int[(size_t)b * K_SZ + ks];
}

extern "C" void kernel_launch(void* const* d_in, const int* in_sizes, int n_in,
                              void* d_out, int out_size, void* d_ws, size_t ws_size,
                              hipStream_t stream) {
    const float* h0       = (const float*)d_in[0];
    const float* t_int    = (const float*)d_in[1];
    const float* U_int    = (const float*)d_in[2];
    const int*   int_lens = (const int*)d_in[3];
    const float* Wp       = (const float*)d_in[4];
    const float* bp       = (const float*)d_in[5];
    const float* gamma    = (const float*)d_in[6];
    const float* beta     = (const float*)d_in[7];
    const float* A_log    = (const float*)d_in[8];
    const float* Bmat     = (const float*)d_in[9];
    const float* Ws       = (const float*)d_in[10];
    const float* bs       = (const float*)d_in[11];

    float* out = (float*)d_out;
    float* Bu   = (float*)d_ws;                                    // B*K*D_H f32
    float* xbuf = (float*)((char*)d_ws + (size_t)B_SZ * K_SZ * D_H * sizeof(float));

    size_t lds_bytes = (size_t)D_H * KPL * sizeof(uint16_t);   // 139264
    im_phase1<<<dim3(P1_BLOCKS), dim3(P1_THREADS), lds_bytes, stream>>>(
        t_int, U_int, Wp, bp, gamma, beta, Bmat, Ws, bs, Bu, xbuf);

    im_times<<<dim3(((K_SZ + 1) * B_SZ + 255) / 256), dim3(256), 0, stream>>>(t_int, out);

    im_scan<<<dim3(B_SZ), dim3(512), 0, stream>>>(h0, int_lens, A_log, Bu, xbuf, out);
}

// Round 8
// 680.369 us; speedup vs baseline: 1.1210x; 1.0115x over previous
//
#include <hip/hip_runtime.h>
#include <cstdint>
#include <math.h>

#define B_SZ 512
#define K_SZ 1024
#define N_INTV 5
#define D_U 32
#define D_H 64
#define SEL_OUT (D_H * D_U + D_H + 1) /* 2113 */

#define KP 1056            /* logical K: 1024 quadratic + 32 linear */
#define KPL 1088           /* LDS row stride: [0,1024) quad | [1024,1056) tail | pad */
#define NTILES (B_SZ * K_SZ / 32)   /* 16384 tiles of 32 events */
#define P1_BLOCKS 256
#define P1_THREADS 512     /* 8 waves */

typedef __attribute__((ext_vector_type(8))) short bf16x8;
typedef __attribute__((ext_vector_type(16))) float f32x16;
typedef __attribute__((ext_vector_type(2))) float f32x2;

__device__ inline uint16_t f2bf_rne(float f) {
    uint32_t u = __builtin_bit_cast(uint32_t, f);
    uint32_t r = (u + 0x7FFFu + ((u >> 16) & 1u)) >> 16;
    return (uint16_t)r;
}
// pack two fp32 -> bf16x2 dword by byte-perm truncation (1 VALU per pair)
__device__ inline uint32_t pack_bf16_trunc(float lo, float hi) {
    return __builtin_amdgcn_perm(__builtin_bit_cast(uint32_t, hi),
                                 __builtin_bit_cast(uint32_t, lo), 0x07060302u);
}
__device__ inline float rdlane(float v, int l) {
    return __builtin_bit_cast(float,
        (uint32_t)__builtin_amdgcn_readlane(__builtin_bit_cast(uint32_t, v), l));
}

// ---------------- Phase 1: 32x32x16 MFMA quadratic-form GEMM -------------
// Bu[e][h] = p(e) . W[h], p = [u (x) u (1024) | u (32)], K = 1056.
// LDS row stride 1088. Quadratic region swizzled elem^=(h&7)<<3 (closed in
// [0,1024)); 32-elem tail swizzled elem^=(h&3)<<3 (closed in [1024,1056)).
// amdgpu_waves_per_eu(1,2): LDS (139 KB) caps us at 1 block/CU = 2 waves/EU;
// min=1 lifts the VGPR budget to 512 so the ~190-reg live set doesn't spill.
// (R6/R7 lesson: __launch_bounds__ 2nd arg left the cap at 128 -> 1 GB/disp
// of scratch spill traffic = the whole kernel time.)
__global__ __launch_bounds__(P1_THREADS)
__attribute__((amdgpu_waves_per_eu(1, 2)))
void im_phase1(
    const float* __restrict__ t_int, const float* __restrict__ U_int,
    const float* __restrict__ Wp, const float* __restrict__ bp,
    const float* __restrict__ gamma, const float* __restrict__ beta,
    const float* __restrict__ Bmat, const float* __restrict__ Ws,
    const float* __restrict__ bs,
    float* __restrict__ Bu, float* __restrict__ xbuf)
{
    extern __shared__ uint16_t Wl[];   // [64][KPL] bf16, swizzled
    const int tid = threadIdx.x;

    // ---- stage W (once per block) ----
    for (int idx = tid; idx < D_H * KP; idx += P1_THREADS) {
        int h = idx / KP;
        int k = idx - h * KP;
        float v;
        int dst;
        if (k < 1024) {
            int i = k >> 5, j = k & 31;
            v = Ws[(size_t)(h * D_U + i) * D_U + j];
            dst = k ^ ((h & 7) << 3);
        } else {
            int i = k - 1024;
            v = Bmat[h * D_U + i] + bs[h * D_U + i];
            dst = 1024 + (i ^ ((h & 3) << 3));
        }
        Wl[h * KPL + dst] = f2bf_rne(v);
    }
    __syncthreads();

    const int wid  = tid >> 6;
    const int lane = tid & 63;
    const int colr = lane & 31;   // event row (A) / h col (B)
    const int half = lane >> 5;   // k-octet selector
    const int xr   = (lane & 7) << 3;   // quad-region XOR (h&7 == lane&7)
    const int lowp = (8 * half) ^ (xr & 8);

    // quad-region LDS byte offsets: read step s (<64) at boff[nt][s&3] + (s>>2)*128
    uint32_t boff[2][4];
    #pragma unroll
    for (int nt = 0; nt < 2; ++nt)
        #pragma unroll
        for (int m = 0; m < 4; ++m)
            boff[nt][m] = 2u * (((nt * 32 + colr) * KPL) + lowp +
                                (((m ^ ((xr >> 4) & 3)) & 3) << 4));
    // tail LDS byte offsets (steps 64, 65): XOR confined to (h&3)<<3
    uint32_t toff[2][2];
    #pragma unroll
    for (int nt = 0; nt < 2; ++nt) {
        int e0 = 1024 + ((8 * half) ^ ((colr & 3) << 3));
        int e1 = 1024 + ((16 + 8 * half) ^ ((colr & 3) << 3));
        toff[nt][0] = 2u * ((nt * 32 + colr) * KPL + e0);
        toff[nt][1] = 2u * ((nt * 32 + colr) * KPL + e1);
    }

    for (int tile = blockIdx.x * 8 + wid; tile < NTILES; tile += P1_BLOCKS * 8) {
        const int base = tile << 5;
        const int ev   = base + colr;   // this lane's event (2x redundant across half)

        // ---- load U (5 feats), project 5->32, layernorm ----
        float Uin[N_INTV];
        #pragma unroll
        for (int c = 0; c < N_INTV; ++c)
            Uin[c] = U_int[(size_t)ev * N_INTV + c];

        float u[D_U];
        #pragma unroll
        for (int d = 0; d < D_U; ++d) {
            float acc = bp[d];
            #pragma unroll
            for (int c = 0; c < N_INTV; ++c)
                acc = fmaf(Wp[d * N_INTV + c], Uin[c], acc);
            u[d] = acc;
        }
        float mu = 0.f;
        #pragma unroll
        for (int d = 0; d < D_U; ++d) mu += u[d];
        mu *= (1.f / D_U);
        float m2 = 0.f;
        #pragma unroll
        for (int d = 0; d < D_U; ++d) { float t = u[d] - mu; m2 += t * t; }
        float rs = rsqrtf(m2 * (1.f / D_U) + 1e-5f);
        #pragma unroll
        for (int d = 0; d < D_U; ++d)
            u[d] = (u[d] - mu) * rs * gamma[d] + beta[d];

        // ---- xbuf (one lane per event) ----
        if (half == 0) {
            const float* wr = Ws + (size_t)(SEL_OUT - 1) * D_U;
            float s = bs[SEL_OUT - 1];
            #pragma unroll
            for (int j = 0; j < D_U; ++j) s = fmaf(wr[j], u[j], s);
            float sp = fmaxf(s, 0.f) + log1pf(expf(-fabsf(s)));
            int kk = ev & (K_SZ - 1);
            float dtv = 0.f;
            if (kk > 0) dtv = fmaxf(t_int[ev] - t_int[ev - 1], 0.f);
            xbuf[ev] = dtv * sp;
        }

        // ---- this lane's j-slices as f32x2 pairs (select on half) ----
        f32x2 v2[8];
        #pragma unroll
        for (int p = 0; p < 4; ++p) {
            f32x2 a0 = { u[2 * p],      u[2 * p + 1]      };
            f32x2 a1 = { u[8 + 2 * p],  u[9 + 2 * p]      };
            f32x2 b0 = { u[16 + 2 * p], u[17 + 2 * p]     };
            f32x2 b1 = { u[24 + 2 * p], u[25 + 2 * p]     };
            v2[p]     = half ? a1 : a0;   // even step slice: jj0 = 8*half
            v2[4 + p] = half ? b1 : b0;   // odd  step slice: jj0 = 16 + 8*half
        }

        f32x16 acc0, acc1;
        #pragma unroll
        for (int i = 0; i < 16; ++i) { acc0[i] = 0.f; acc1[i] = 0.f; }

        union AF { uint32_t w[4]; bf16x8 v; };

        // ---- 64 quadratic K-steps ----
        #pragma unroll
        for (int s = 0; s < 64; ++s) {
            float uts = u[s >> 1];
            f32x2 utv = { uts, uts };
            const int sl = (s & 1) * 4;
            AF af;
            f32x2 p0 = utv * v2[sl + 0];
            f32x2 p1 = utv * v2[sl + 1];
            f32x2 p2 = utv * v2[sl + 2];
            f32x2 p3 = utv * v2[sl + 3];
            af.w[0] = pack_bf16_trunc(p0.x, p0.y);
            af.w[1] = pack_bf16_trunc(p1.x, p1.y);
            af.w[2] = pack_bf16_trunc(p2.x, p2.y);
            af.w[3] = pack_bf16_trunc(p3.x, p3.y);
            bf16x8 b0 = *(const bf16x8*)((const char*)Wl + boff[0][s & 3] + (s >> 2) * 128);
            bf16x8 b1 = *(const bf16x8*)((const char*)Wl + boff[1][s & 3] + (s >> 2) * 128);
            acc0 = __builtin_amdgcn_mfma_f32_32x32x16_bf16(af.v, b0, acc0, 0, 0, 0);
            acc1 = __builtin_amdgcn_mfma_f32_32x32x16_bf16(af.v, b1, acc1, 0, 0, 0);
        }
        // ---- 2 linear tail steps (p = u) ----
        #pragma unroll
        for (int s = 0; s < 2; ++s) {
            const int sl = s * 4;
            AF af;
            af.w[0] = pack_bf16_trunc(v2[sl + 0].x, v2[sl + 0].y);
            af.w[1] = pack_bf16_trunc(v2[sl + 1].x, v2[sl + 1].y);
            af.w[2] = pack_bf16_trunc(v2[sl + 2].x, v2[sl + 2].y);
            af.w[3] = pack_bf16_trunc(v2[sl + 3].x, v2[sl + 3].y);
            bf16x8 b0 = *(const bf16x8*)((const char*)Wl + toff[0][s]);
            bf16x8 b1 = *(const bf16x8*)((const char*)Wl + toff[1][s]);
            acc0 = __builtin_amdgcn_mfma_f32_32x32x16_bf16(af.v, b0, acc0, 0, 0, 0);
            acc1 = __builtin_amdgcn_mfma_f32_32x32x16_bf16(af.v, b1, acc1, 0, 0, 0);
        }

        // ---- C store (plain f32): row(reg)=(reg&3)+8*(reg>>2)+4*half ----
        float* bo = Bu + (size_t)base * D_H;
        #pragma unroll
        for (int rg = 0; rg < 16; ++rg) {
            int r0 = (rg & 3) + 8 * (rg >> 2) + 4 * half;
            bo[(size_t)r0 * D_H + colr]      = acc0[rg];
            bo[(size_t)r0 * D_H + 32 + colr] = acc1[rg];
        }
    }
}

// ---------------- Phase 2: chunked scan, one block per batch row ----------
// 8 waves = 8 chunks of 128 steps. Pass 1: per-chunk affine (P,Q) with Bu
// (f32) packed to bf16 pairs parked in 64 VGPRs. Block scan via LDS. Pass 2:
// replay from regs.
#define NCH 8
#define CLEN 128
__global__ __launch_bounds__(512) void im_scan(
    const float* __restrict__ h0, const int* __restrict__ int_lens,
    const float* __restrict__ A_log,
    const float* __restrict__ Bu, const float* __restrict__ xbuf,
    float* __restrict__ out)
{
    __shared__ float Pl[NCH][64], Ql[NCH][64];
    const int b = blockIdx.x;
    const int wave = threadIdx.x >> 6;
    const int lane = threadIdx.x & 63;
    const int k0 = wave * CLEN;

    float A = -__expf(A_log[lane]);
    float invA = 1.f / A;
    int len = int_lens[b];

    float xv0 = xbuf[(size_t)b * K_SZ + k0 + lane];
    float xv1 = xbuf[(size_t)b * K_SZ + k0 + 64 + lane];
    const float* bup = Bu + ((size_t)(b * K_SZ + k0)) * D_H + lane;

    uint32_t bu[64];
    float P = 1.f, Q = 0.f;
    #pragma unroll
    for (int s2 = 0; s2 < 64; ++s2) {
        float lo = bup[(size_t)(2 * s2) * D_H];
        float hi = bup[(size_t)(2 * s2 + 1) * D_H];
        bu[s2] = pack_bf16_trunc(lo, hi);
        {
            const int t = 2 * s2;
            float x = (t < 64) ? rdlane(xv0, t & 63) : rdlane(xv1, t & 63);
            float eA = __expf(A * x);
            bool act = (k0 + t) < len;
            float Pf = act ? eA : 1.f;
            float cf = act ? (eA - 1.f) * invA * lo : 0.f;
            P *= Pf;
            Q = fmaf(Pf, Q, cf);
        }
        {
            const int t = 2 * s2 + 1;
            float x = (t < 64) ? rdlane(xv0, t & 63) : rdlane(xv1, t & 63);
            float eA = __expf(A * x);
            bool act = (k0 + t) < len;
            float Pf = act ? eA : 1.f;
            float cf = act ? (eA - 1.f) * invA * hi : 0.f;
            P *= Pf;
            Q = fmaf(Pf, Q, cf);
        }
    }
    Pl[wave][lane] = P;
    Ql[wave][lane] = Q;
    __syncthreads();

    // chunk start state
    float hv = h0[b * D_H + lane];
    for (int cc = 0; cc < wave; ++cc)
        hv = fmaf(Pl[cc][lane], hv, Ql[cc][lane]);

    float* times  = out + (size_t)B_SZ * D_H;
    float* states = times + (size_t)(K_SZ + 1) * B_SZ;
    if (wave == 0)
        states[(size_t)b * D_H + lane] = hv;   // states[0] = h0

    // replay from registers (Bu truncated to bf16 in-reg)
    #pragma unroll
    for (int s2 = 0; s2 < 64; ++s2) {
        uint32_t w = bu[s2];
        {
            const int t = 2 * s2;
            float Buf = __builtin_bit_cast(float, w << 16);
            float x = (t < 64) ? rdlane(xv0, t & 63) : rdlane(xv1, t & 63);
            float eA = __expf(A * x);
            float hn = fmaf(eA, hv, (eA - 1.f) * invA * Buf);
            hv = ((k0 + t) < len) ? hn : hv;
            states[((size_t)(k0 + t + 1) * B_SZ + b) * D_H + lane] = hv;
        }
        {
            const int t = 2 * s2 + 1;
            float Buf = __builtin_bit_cast(float, w & 0xFFFF0000u);
            float x = (t < 64) ? rdlane(xv0, t & 63) : rdlane(xv1, t & 63);
            float eA = __expf(A * x);
            float hn = fmaf(eA, hv, (eA - 1.f) * invA * Buf);
            hv = ((k0 + t) < len) ? hn : hv;
            states[((size_t)(k0 + t + 1) * B_SZ + b) * D_H + lane] = hv;
        }
    }
    if (wave == NCH - 1)
        out[b * D_H + lane] = hv;   // h_final
}

// ---------------- times: (K+1, B) transpose of t_int ----------------------
__global__ __launch_bounds__(256) void im_times(
    const float* __restrict__ t_int, float* __restrict__ out)
{
    int idx = blockIdx.x * blockDim.x + threadIdx.x;
    if (idx >= (K_SZ + 1) * B_SZ) return;
    int kp = idx >> 9;            // / B_SZ
    int b  = idx & (B_SZ - 1);
    int ks = (kp == 0) ? 0 : kp - 1;
    float* times = out + (size_t)B_SZ * D_H;
    times[idx] = t_int[(size_t)b * K_SZ + ks];
}

extern "C" void kernel_launch(void* const* d_in, const int* in_sizes, int n_in,
                              void* d_out, int out_size, void* d_ws, size_t ws_size,
                              hipStream_t stream) {
    const float* h0       = (const float*)d_in[0];
    const float* t_int    = (const float*)d_in[1];
    const float* U_int    = (const float*)d_in[2];
    const int*   int_lens = (const int*)d_in[3];
    const float* Wp       = (const float*)d_in[4];
    const float* bp       = (const float*)d_in[5];
    const float* gamma    = (const float*)d_in[6];
    const float* beta     = (const float*)d_in[7];
    const float* A_log    = (const float*)d_in[8];
    const float* Bmat     = (const float*)d_in[9];
    const float* Ws       = (const float*)d_in[10];
    const float* bs       = (const float*)d_in[11];

    float* out = (float*)d_out;
    float* Bu   = (float*)d_ws;                                    // B*K*D_H f32
    float* xbuf = (float*)((char*)d_ws + (size_t)B_SZ * K_SZ * D_H * sizeof(float));

    size_t lds_bytes = (size_t)D_H * KPL * sizeof(uint16_t);   // 139264
    im_phase1<<<dim3(P1_BLOCKS), dim3(P1_THREADS), lds_bytes, stream>>>(
        t_int, U_int, Wp, bp, gamma, beta, Bmat, Ws, bs, Bu, xbuf);

    im_times<<<dim3(((K_SZ + 1) * B_SZ + 255) / 256), dim3(256), 0, stream>>>(t_int, out);

    im_scan<<<dim3(B_SZ), dim3(512), 0, stream>>>(h0, int_lens, A_log, Bu, xbuf, out);
}

// Round 9
// 664.119 us; speedup vs baseline: 1.1484x; 1.0245x over previous
//
#include <hip/hip_runtime.h>
#include <cstdint>
#include <math.h>

#define B_SZ 512
#define K_SZ 1024
#define N_INTV 5
#define D_U 32
#define D_H 64
#define SEL_OUT (D_H * D_U + D_H + 1) /* 2113 */

#define KP 1056            /* logical K: 1024 quadratic + 32 linear */
#define KPL 1088           /* LDS row stride: [0,1024) quad | [1024,1056) tail | pad */
#define NTILES (B_SZ * K_SZ / 32)   /* 16384 tiles of 32 events */
#define P1_BLOCKS 256
#define P1_THREADS 512     /* 8 waves */

typedef __attribute__((ext_vector_type(8))) short bf16x8;
typedef __attribute__((ext_vector_type(16))) float f32x16;
typedef __attribute__((ext_vector_type(2))) float f32x2;

__device__ inline uint16_t f2bf_rne(float f) {
    uint32_t u = __builtin_bit_cast(uint32_t, f);
    uint32_t r = (u + 0x7FFFu + ((u >> 16) & 1u)) >> 16;
    return (uint16_t)r;
}
// pack two fp32 -> bf16x2 dword by byte-perm truncation (1 VALU per pair)
__device__ inline uint32_t pack_bf16_trunc(float lo, float hi) {
    return __builtin_amdgcn_perm(__builtin_bit_cast(uint32_t, hi),
                                 __builtin_bit_cast(uint32_t, lo), 0x07060302u);
}
__device__ inline float rdlane(float v, int l) {
    return __builtin_bit_cast(float,
        (uint32_t)__builtin_amdgcn_readlane(__builtin_bit_cast(uint32_t, v), l));
}

// ---------------- Phase 1: 32x32x16 MFMA quadratic-form GEMM -------------
// Bu[e][h] = p(e) . W[h], p = [u (x) u (1024) | u (32)], K = 1056.
// R8 lesson (rule #20): the 64-step K-loop was too big for #pragma unroll,
// so u/v2/boff became runtime-indexed -> allocated in SCRATCH -> ~700 MB of
// spill-fill traffic per dispatch = the whole kernel time, immune to
// occupancy attributes. Fix: macro-generated straight-line K-steps with
// constexpr indices; SROA then promotes every array to registers.
__global__ __launch_bounds__(P1_THREADS)
__attribute__((amdgpu_waves_per_eu(1, 2)))
void im_phase1(
    const float* __restrict__ t_int, const float* __restrict__ U_int,
    const float* __restrict__ Wp, const float* __restrict__ bp,
    const float* __restrict__ gamma, const float* __restrict__ beta,
    const float* __restrict__ Bmat, const float* __restrict__ Ws,
    const float* __restrict__ bs,
    float* __restrict__ Bu, float* __restrict__ xbuf)
{
    extern __shared__ uint16_t Wl[];   // [64][KPL] bf16, swizzled
    const int tid = threadIdx.x;

    // ---- stage W (once per block) ----
    for (int idx = tid; idx < D_H * KP; idx += P1_THREADS) {
        int h = idx / KP;
        int k = idx - h * KP;
        float v;
        int dst;
        if (k < 1024) {
            int i = k >> 5, j = k & 31;
            v = Ws[(size_t)(h * D_U + i) * D_U + j];
            dst = k ^ ((h & 7) << 3);
        } else {
            int i = k - 1024;
            v = Bmat[h * D_U + i] + bs[h * D_U + i];
            dst = 1024 + (i ^ ((h & 3) << 3));
        }
        Wl[h * KPL + dst] = f2bf_rne(v);
    }
    __syncthreads();

    const int wid  = tid >> 6;
    const int lane = tid & 63;
    const int colr = lane & 31;   // event row (A) / h col (B)
    const int half = lane >> 5;   // k-octet selector
    const int xr   = (lane & 7) << 3;   // quad-region XOR (h&7 == lane&7)
    const int lowp = (8 * half) ^ (xr & 8);

    // quad-region LDS byte offsets: step s reads boffN[s&3] + (s>>2)*128
    uint32_t boff0[4], boff1[4];
    #pragma unroll
    for (int m = 0; m < 4; ++m) {
        const uint32_t e = (uint32_t)(lowp + (((m ^ ((xr >> 4) & 3)) & 3) << 4));
        boff0[m] = 2u * ((uint32_t)(colr * KPL) + e);
        boff1[m] = 2u * ((uint32_t)((32 + colr) * KPL) + e);
    }
    // tail LDS byte offsets (steps 64, 65): XOR confined to (h&3)<<3
    uint32_t toff0[2], toff1[2];
    {
        const int e0 = 1024 + ((8 * half) ^ ((colr & 3) << 3));
        const int e1 = 1024 + ((16 + 8 * half) ^ ((colr & 3) << 3));
        toff0[0] = 2u * (colr * KPL + e0);
        toff0[1] = 2u * (colr * KPL + e1);
        toff1[0] = 2u * ((32 + colr) * KPL + e0);
        toff1[1] = 2u * ((32 + colr) * KPL + e1);
    }

    for (int tile = blockIdx.x * 8 + wid; tile < NTILES; tile += P1_BLOCKS * 8) {
        const int base = tile << 5;
        const int ev   = base + colr;   // this lane's event (2x redundant across half)

        // ---- load U (5 feats), project 5->32, layernorm ----
        float Uin[N_INTV];
        #pragma unroll
        for (int c = 0; c < N_INTV; ++c)
            Uin[c] = U_int[(size_t)ev * N_INTV + c];

        float u[D_U];
        #pragma unroll
        for (int d = 0; d < D_U; ++d) {
            float acc = bp[d];
            #pragma unroll
            for (int c = 0; c < N_INTV; ++c)
                acc = fmaf(Wp[d * N_INTV + c], Uin[c], acc);
            u[d] = acc;
        }
        float mu = 0.f;
        #pragma unroll
        for (int d = 0; d < D_U; ++d) mu += u[d];
        mu *= (1.f / D_U);
        float m2 = 0.f;
        #pragma unroll
        for (int d = 0; d < D_U; ++d) { float t = u[d] - mu; m2 += t * t; }
        float rs = rsqrtf(m2 * (1.f / D_U) + 1e-5f);
        #pragma unroll
        for (int d = 0; d < D_U; ++d)
            u[d] = (u[d] - mu) * rs * gamma[d] + beta[d];

        // ---- xbuf (one lane per event) ----
        if (half == 0) {
            const float* wr = Ws + (size_t)(SEL_OUT - 1) * D_U;
            float s = bs[SEL_OUT - 1];
            #pragma unroll
            for (int j = 0; j < D_U; ++j) s = fmaf(wr[j], u[j], s);
            float sp = fmaxf(s, 0.f) + log1pf(expf(-fabsf(s)));
            int kk = ev & (K_SZ - 1);
            float dtv = 0.f;
            if (kk > 0) dtv = fmaxf(t_int[ev] - t_int[ev - 1], 0.f);
            xbuf[ev] = dtv * sp;
        }

        // ---- this lane's j-slices as f32x2 pairs (explicit, const idx) ----
        f32x2 v2[8];
        v2[0] = half ? (f32x2){u[ 8], u[ 9]} : (f32x2){u[ 0], u[ 1]};
        v2[1] = half ? (f32x2){u[10], u[11]} : (f32x2){u[ 2], u[ 3]};
        v2[2] = half ? (f32x2){u[12], u[13]} : (f32x2){u[ 4], u[ 5]};
        v2[3] = half ? (f32x2){u[14], u[15]} : (f32x2){u[ 6], u[ 7]};
        v2[4] = half ? (f32x2){u[24], u[25]} : (f32x2){u[16], u[17]};
        v2[5] = half ? (f32x2){u[26], u[27]} : (f32x2){u[18], u[19]};
        v2[6] = half ? (f32x2){u[28], u[29]} : (f32x2){u[20], u[21]};
        v2[7] = half ? (f32x2){u[30], u[31]} : (f32x2){u[22], u[23]};

        f32x16 acc0 = {0.f,0.f,0.f,0.f,0.f,0.f,0.f,0.f,0.f,0.f,0.f,0.f,0.f,0.f,0.f,0.f};
        f32x16 acc1 = {0.f,0.f,0.f,0.f,0.f,0.f,0.f,0.f,0.f,0.f,0.f,0.f,0.f,0.f,0.f,0.f};

        union AF { uint32_t w[4]; bf16x8 v; };

        // ---- 64 quadratic K-steps, straight-line, constexpr indices ----
#define QSTEP(S) { \
        constexpr int s_  = (S); \
        constexpr int sl_ = (s_ & 1) * 4; \
        const float uts = u[s_ >> 1]; \
        const f32x2 utv = { uts, uts }; \
        AF af; \
        const f32x2 p0 = utv * v2[sl_ + 0]; \
        const f32x2 p1 = utv * v2[sl_ + 1]; \
        const f32x2 p2 = utv * v2[sl_ + 2]; \
        const f32x2 p3 = utv * v2[sl_ + 3]; \
        af.w[0] = pack_bf16_trunc(p0.x, p0.y); \
        af.w[1] = pack_bf16_trunc(p1.x, p1.y); \
        af.w[2] = pack_bf16_trunc(p2.x, p2.y); \
        af.w[3] = pack_bf16_trunc(p3.x, p3.y); \
        const bf16x8 b0_ = *(const bf16x8*)((const char*)Wl + boff0[s_ & 3] + (s_ >> 2) * 128); \
        const bf16x8 b1_ = *(const bf16x8*)((const char*)Wl + boff1[s_ & 3] + (s_ >> 2) * 128); \
        acc0 = __builtin_amdgcn_mfma_f32_32x32x16_bf16(af.v, b0_, acc0, 0, 0, 0); \
        acc1 = __builtin_amdgcn_mfma_f32_32x32x16_bf16(af.v, b1_, acc1, 0, 0, 0); \
    }
#define QSTEP4(S)  QSTEP(S) QSTEP((S)+1) QSTEP((S)+2) QSTEP((S)+3)
#define QSTEP16(S) QSTEP4(S) QSTEP4((S)+4) QSTEP4((S)+8) QSTEP4((S)+12)
        QSTEP16(0) QSTEP16(16) QSTEP16(32) QSTEP16(48)
#undef QSTEP16
#undef QSTEP4
#undef QSTEP

        // ---- 2 linear tail steps (p = u), straight-line ----
#define TSTEP(S) { \
        constexpr int s_  = (S); \
        constexpr int sl_ = (s_) * 4; \
        AF af; \
        af.w[0] = pack_bf16_trunc(v2[sl_ + 0].x, v2[sl_ + 0].y); \
        af.w[1] = pack_bf16_trunc(v2[sl_ + 1].x, v2[sl_ + 1].y); \
        af.w[2] = pack_bf16_trunc(v2[sl_ + 2].x, v2[sl_ + 2].y); \
        af.w[3] = pack_bf16_trunc(v2[sl_ + 3].x, v2[sl_ + 3].y); \
        const bf16x8 b0_ = *(const bf16x8*)((const char*)Wl + toff0[s_]); \
        const bf16x8 b1_ = *(const bf16x8*)((const char*)Wl + toff1[s_]); \
        acc0 = __builtin_amdgcn_mfma_f32_32x32x16_bf16(af.v, b0_, acc0, 0, 0, 0); \
        acc1 = __builtin_amdgcn_mfma_f32_32x32x16_bf16(af.v, b1_, acc1, 0, 0, 0); \
    }
        TSTEP(0) TSTEP(1)
#undef TSTEP

        // ---- C store, straight-line: row(reg)=(reg&3)+8*(reg>>2)+4*half ----
        float* bo = Bu + (size_t)base * D_H;
        const int r4 = 4 * half;
#define CSTORE(RG) { \
        constexpr int rg_ = (RG); \
        constexpr int r0_ = (rg_ & 3) + 8 * (rg_ >> 2); \
        bo[(size_t)(r0_ + r4) * D_H + colr]      = acc0[rg_]; \
        bo[(size_t)(r0_ + r4) * D_H + 32 + colr] = acc1[rg_]; \
    }
#define CSTORE4(S) CSTORE(S) CSTORE((S)+1) CSTORE((S)+2) CSTORE((S)+3)
        CSTORE4(0) CSTORE4(4) CSTORE4(8) CSTORE4(12)
#undef CSTORE4
#undef CSTORE
    }
}

// ---------------- Phase 2: chunked scan, one block per batch row ----------
// 8 waves = 8 chunks of 128 steps. Pass 1: per-chunk affine (P,Q) with Bu
// (f32) packed to bf16 pairs parked in 64 VGPRs. Block scan via LDS. Pass 2:
// replay from regs.
#define NCH 8
#define CLEN 128
__global__ __launch_bounds__(512) void im_scan(
    const float* __restrict__ h0, const int* __restrict__ int_lens,
    const float* __restrict__ A_log,
    const float* __restrict__ Bu, const float* __restrict__ xbuf,
    float* __restrict__ out)
{
    __shared__ float Pl[NCH][64], Ql[NCH][64];
    const int b = blockIdx.x;
    const int wave = threadIdx.x >> 6;
    const int lane = threadIdx.x & 63;
    const int k0 = wave * CLEN;

    float A = -__expf(A_log[lane]);
    float invA = 1.f / A;
    int len = int_lens[b];

    float xv0 = xbuf[(size_t)b * K_SZ + k0 + lane];
    float xv1 = xbuf[(size_t)b * K_SZ + k0 + 64 + lane];
    const float* bup = Bu + ((size_t)(b * K_SZ + k0)) * D_H + lane;

    uint32_t bu[64];
    float P = 1.f, Q = 0.f;
    #pragma unroll
    for (int s2 = 0; s2 < 64; ++s2) {
        float lo = bup[(size_t)(2 * s2) * D_H];
        float hi = bup[(size_t)(2 * s2 + 1) * D_H];
        bu[s2] = pack_bf16_trunc(lo, hi);
        {
            const int t = 2 * s2;
            float x = (t < 64) ? rdlane(xv0, t & 63) : rdlane(xv1, t & 63);
            float eA = __expf(A * x);
            bool act = (k0 + t) < len;
            float Pf = act ? eA : 1.f;
            float cf = act ? (eA - 1.f) * invA * lo : 0.f;
            P *= Pf;
            Q = fmaf(Pf, Q, cf);
        }
        {
            const int t = 2 * s2 + 1;
            float x = (t < 64) ? rdlane(xv0, t & 63) : rdlane(xv1, t & 63);
            float eA = __expf(A * x);
            bool act = (k0 + t) < len;
            float Pf = act ? eA : 1.f;
            float cf = act ? (eA - 1.f) * invA * hi : 0.f;
            P *= Pf;
            Q = fmaf(Pf, Q, cf);
        }
    }
    Pl[wave][lane] = P;
    Ql[wave][lane] = Q;
    __syncthreads();

    // chunk start state
    float hv = h0[b * D_H + lane];
    for (int cc = 0; cc < wave; ++cc)
        hv = fmaf(Pl[cc][lane], hv, Ql[cc][lane]);

    float* times  = out + (size_t)B_SZ * D_H;
    float* states = times + (size_t)(K_SZ + 1) * B_SZ;
    if (wave == 0)
        states[(size_t)b * D_H + lane] = hv;   // states[0] = h0

    // replay from registers (Bu truncated to bf16 in-reg)
    #pragma unroll
    for (int s2 = 0; s2 < 64; ++s2) {
        uint32_t w = bu[s2];
        {
            const int t = 2 * s2;
            float Buf = __builtin_bit_cast(float, w << 16);
            float x = (t < 64) ? rdlane(xv0, t & 63) : rdlane(xv1, t & 63);
            float eA = __expf(A * x);
            float hn = fmaf(eA, hv, (eA - 1.f) * invA * Buf);
            hv = ((k0 + t) < len) ? hn : hv;
            states[((size_t)(k0 + t + 1) * B_SZ + b) * D_H + lane] = hv;
        }
        {
            const int t = 2 * s2 + 1;
            float Buf = __builtin_bit_cast(float, w & 0xFFFF0000u);
            float x = (t < 64) ? rdlane(xv0, t & 63) : rdlane(xv1, t & 63);
            float eA = __expf(A * x);
            float hn = fmaf(eA, hv, (eA - 1.f) * invA * Buf);
            hv = ((k0 + t) < len) ? hn : hv;
            states[((size_t)(k0 + t + 1) * B_SZ + b) * D_H + lane] = hv;
        }
    }
    if (wave == NCH - 1)
        out[b * D_H + lane] = hv;   // h_final
}

// ---------------- times: (K+1, B) transpose of t_int ----------------------
__global__ __launch_bounds__(256) void im_times(
    const float* __restrict__ t_int, float* __restrict__ out)
{
    int idx = blockIdx.x * blockDim.x + threadIdx.x;
    if (idx >= (K_SZ + 1) * B_SZ) return;
    int kp = idx >> 9;            // / B_SZ
    int b  = idx & (B_SZ - 1);
    int ks = (kp == 0) ? 0 : kp - 1;
    float* times = out + (size_t)B_SZ * D_H;
    times[idx] = t_int[(size_t)b * K_SZ + ks];
}

extern "C" void kernel_launch(void* const* d_in, const int* in_sizes, int n_in,
                              void* d_out, int out_size, void* d_ws, size_t ws_size,
                              hipStream_t stream) {
    const float* h0       = (const float*)d_in[0];
    const float* t_int    = (const float*)d_in[1];
    const float* U_int    = (const float*)d_in[2];
    const int*   int_lens = (const int*)d_in[3];
    const float* Wp       = (const float*)d_in[4];
    const float* bp       = (const float*)d_in[5];
    const float* gamma    = (const float*)d_in[6];
    const float* beta     = (const float*)d_in[7];
    const float* A_log    = (const float*)d_in[8];
    const float* Bmat     = (const float*)d_in[9];
    const float* Ws       = (const float*)d_in[10];
    const float* bs       = (const float*)d_in[11];

    float* out = (float*)d_out;
    float* Bu   = (float*)d_ws;                                    // B*K*D_H f32
    float* xbuf = (float*)((char*)d_ws + (size_t)B_SZ * K_SZ * D_H * sizeof(float));

    size_t lds_bytes = (size_t)D_H * KPL * sizeof(uint16_t);   // 139264
    im_phase1<<<dim3(P1_BLOCKS), dim3(P1_THREADS), lds_bytes, stream>>>(
        t_int, U_int, Wp, bp, gamma, beta, Bmat, Ws, bs, Bu, xbuf);

    im_times<<<dim3(((K_SZ + 1) * B_SZ + 255) / 256), dim3(256), 0, stream>>>(t_int, out);

    im_scan<<<dim3(B_SZ), dim3(512), 0, stream>>>(h0, int_lens, A_log, Bu, xbuf, out);
}

// Round 10
// 518.439 us; speedup vs baseline: 1.4711x; 1.2810x over previous
//
#include <hip/hip_runtime.h>
#include <cstdint>
#include <math.h>

#define B_SZ 512
#define K_SZ 1024
#define N_INTV 5
#define D_U 32
#define D_H 64
#define SEL_OUT (D_H * D_U + D_H + 1) /* 2113 */

#define KP 1056            /* logical K: 1024 quadratic + 32 linear */
#define KPL 1088           /* LDS row stride: [0,1024) quad | [1024,1056) tail | pad */
#define NTILES (B_SZ * K_SZ / 32)   /* 16384 tiles of 32 events */
#define P1_BLOCKS 256
#define P1_THREADS 512     /* 8 waves */

typedef __attribute__((ext_vector_type(8))) short bf16x8;
typedef __attribute__((ext_vector_type(16))) float f32x16;

__device__ inline uint16_t f2bf_rne(float f) {
    uint32_t u = __builtin_bit_cast(uint32_t, f);
    uint32_t r = (u + 0x7FFFu + ((u >> 16) & 1u)) >> 16;
    return (uint16_t)r;
}
// pack two fp32 -> bf16x2 dword by byte-perm truncation (1 VALU per pair)
__device__ inline uint32_t pack_bf16_trunc(float lo, float hi) {
    return __builtin_amdgcn_perm(__builtin_bit_cast(uint32_t, hi),
                                 __builtin_bit_cast(uint32_t, lo), 0x07060302u);
}
__device__ inline float bf_lo(uint32_t pk) {   // low bf16 -> f32
    return __builtin_bit_cast(float, pk << 16);
}
__device__ inline float bf_hi(uint32_t pk) {   // high bf16 -> f32
    return __builtin_bit_cast(float, pk & 0xFFFF0000u);
}
__device__ inline float rdlane(float v, int l) {
    return __builtin_bit_cast(float,
        (uint32_t)__builtin_amdgcn_readlane(__builtin_bit_cast(uint32_t, v), l));
}

// ---------------- Phase 1: 32x32x16 MFMA quadratic-form GEMM -------------
// Bu[e][h] = p(e) . W[h], p = [u (x) u (1024) | u (32)], K = 1056.
// R9 lesson: live set (acc32+u32+v2_16+offsets+temps ~150) > the immovable
// 128-VGPR cap -> ~48 regs spilled/refilled per tile = 800 MB scratch traffic
// = the whole kernel time. Fix: u kept as PACKED bf16 (u_pk 16 + v2_pk 8 regs
// instead of 48 f32) -> live set ~100 < 128. Products become bf16*bf16
// (absmax ~0.25, threshold 2.0).
__global__ __launch_bounds__(P1_THREADS)
__attribute__((amdgpu_waves_per_eu(1, 2)))
void im_phase1(
    const float* __restrict__ t_int, const float* __restrict__ U_int,
    const float* __restrict__ Wp, const float* __restrict__ bp,
    const float* __restrict__ gamma, const float* __restrict__ beta,
    const float* __restrict__ Bmat, const float* __restrict__ Ws,
    const float* __restrict__ bs,
    float* __restrict__ Bu, float* __restrict__ xbuf)
{
    extern __shared__ uint16_t Wl[];   // [64][KPL] bf16, swizzled
    const int tid = threadIdx.x;

    // ---- stage W (once per block) ----
    for (int idx = tid; idx < D_H * KP; idx += P1_THREADS) {
        int h = idx / KP;
        int k = idx - h * KP;
        float v;
        int dst;
        if (k < 1024) {
            int i = k >> 5, j = k & 31;
            v = Ws[(size_t)(h * D_U + i) * D_U + j];
            dst = k ^ ((h & 7) << 3);
        } else {
            int i = k - 1024;
            v = Bmat[h * D_U + i] + bs[h * D_U + i];
            dst = 1024 + (i ^ ((h & 3) << 3));
        }
        Wl[h * KPL + dst] = f2bf_rne(v);
    }
    __syncthreads();

    const int wid  = tid >> 6;
    const int lane = tid & 63;
    const int colr = lane & 31;   // event row (A) / h col (B)
    const int half = lane >> 5;   // k-octet selector
    const int xr   = (lane & 7) << 3;   // quad-region XOR (h&7 == lane&7)
    const int lowp = (8 * half) ^ (xr & 8);

    // quad-region LDS byte offsets: step s reads boffN[s&3] + (s>>2)*128
    uint32_t boff0[4], boff1[4];
    #pragma unroll
    for (int m = 0; m < 4; ++m) {
        const uint32_t e = (uint32_t)(lowp + (((m ^ ((xr >> 4) & 3)) & 3) << 4));
        boff0[m] = 2u * ((uint32_t)(colr * KPL) + e);
        boff1[m] = 2u * ((uint32_t)((32 + colr) * KPL) + e);
    }
    // tail LDS byte offsets (steps 64, 65): XOR confined to (h&3)<<3
    uint32_t toff0[2], toff1[2];
    {
        const int e0 = 1024 + ((8 * half) ^ ((colr & 3) << 3));
        const int e1 = 1024 + ((16 + 8 * half) ^ ((colr & 3) << 3));
        toff0[0] = 2u * (colr * KPL + e0);
        toff0[1] = 2u * (colr * KPL + e1);
        toff1[0] = 2u * ((32 + colr) * KPL + e0);
        toff1[1] = 2u * ((32 + colr) * KPL + e1);
    }

    for (int tile = blockIdx.x * 8 + wid; tile < NTILES; tile += P1_BLOCKS * 8) {
        const int base = tile << 5;
        const int ev   = base + colr;   // this lane's event (2x redundant across half)

        // ---- load U (5 feats), project 5->32, layernorm (f32, short-lived) --
        uint32_t u_pk[16];   // u as 16 packed bf16 pairs: the ONLY long-lived u
        {
            float Uin[N_INTV];
            #pragma unroll
            for (int c = 0; c < N_INTV; ++c)
                Uin[c] = U_int[(size_t)ev * N_INTV + c];

            float u[D_U];
            #pragma unroll
            for (int d = 0; d < D_U; ++d) {
                float acc = bp[d];
                #pragma unroll
                for (int c = 0; c < N_INTV; ++c)
                    acc = fmaf(Wp[d * N_INTV + c], Uin[c], acc);
                u[d] = acc;
            }
            float mu = 0.f;
            #pragma unroll
            for (int d = 0; d < D_U; ++d) mu += u[d];
            mu *= (1.f / D_U);
            float m2 = 0.f;
            #pragma unroll
            for (int d = 0; d < D_U; ++d) { float t = u[d] - mu; m2 += t * t; }
            float rs = rsqrtf(m2 * (1.f / D_U) + 1e-5f);
            #pragma unroll
            for (int d = 0; d < D_U; ++d)
                u[d] = (u[d] - mu) * rs * gamma[d] + beta[d];

            // ---- xbuf (one lane per event; uses f32 u before packing) ----
            if (half == 0) {
                const float* wr = Ws + (size_t)(SEL_OUT - 1) * D_U;
                float s = bs[SEL_OUT - 1];
                #pragma unroll
                for (int j = 0; j < D_U; ++j) s = fmaf(wr[j], u[j], s);
                float sp = fmaxf(s, 0.f) + log1pf(expf(-fabsf(s)));
                int kk = ev & (K_SZ - 1);
                float dtv = 0.f;
                if (kk > 0) dtv = fmaxf(t_int[ev] - t_int[ev - 1], 0.f);
                xbuf[ev] = dtv * sp;
            }

            // ---- pack u -> bf16 pairs (RNE) ----
            #pragma unroll
            for (int i = 0; i < 16; ++i)
                u_pk[i] = ((uint32_t)f2bf_rne(u[2 * i + 1]) << 16) | f2bf_rne(u[2 * i]);
        }

        // ---- v2 slices as packed bf16 pairs (8 cndmask, once per tile) ----
        uint32_t v2_pk[8];
        #pragma unroll
        for (int p = 0; p < 4; ++p) {
            v2_pk[p]     = half ? u_pk[4 + p]  : u_pk[p];       // even steps: jj0 = 8*half
            v2_pk[4 + p] = half ? u_pk[12 + p] : u_pk[8 + p];   // odd steps: jj0 = 16+8*half
        }

        f32x16 acc0 = {0.f,0.f,0.f,0.f,0.f,0.f,0.f,0.f,0.f,0.f,0.f,0.f,0.f,0.f,0.f,0.f};
        f32x16 acc1 = {0.f,0.f,0.f,0.f,0.f,0.f,0.f,0.f,0.f,0.f,0.f,0.f,0.f,0.f,0.f,0.f};

        union AF { uint32_t w[4]; bf16x8 v; };

        // ---- 64 quadratic K-steps, straight-line, constexpr indices ----
#define QSTEP(S) { \
        constexpr int s_  = (S); \
        constexpr int sl_ = (s_ & 1) * 4; \
        constexpr int it_ = s_ >> 1; \
        const float uts = (it_ & 1) ? bf_hi(u_pk[it_ >> 1]) : bf_lo(u_pk[it_ >> 1]); \
        AF af; \
        af.w[0] = pack_bf16_trunc(uts * bf_lo(v2_pk[sl_ + 0]), uts * bf_hi(v2_pk[sl_ + 0])); \
        af.w[1] = pack_bf16_trunc(uts * bf_lo(v2_pk[sl_ + 1]), uts * bf_hi(v2_pk[sl_ + 1])); \
        af.w[2] = pack_bf16_trunc(uts * bf_lo(v2_pk[sl_ + 2]), uts * bf_hi(v2_pk[sl_ + 2])); \
        af.w[3] = pack_bf16_trunc(uts * bf_lo(v2_pk[sl_ + 3]), uts * bf_hi(v2_pk[sl_ + 3])); \
        const bf16x8 b0_ = *(const bf16x8*)((const char*)Wl + boff0[s_ & 3] + (s_ >> 2) * 128); \
        const bf16x8 b1_ = *(const bf16x8*)((const char*)Wl + boff1[s_ & 3] + (s_ >> 2) * 128); \
        acc0 = __builtin_amdgcn_mfma_f32_32x32x16_bf16(af.v, b0_, acc0, 0, 0, 0); \
        acc1 = __builtin_amdgcn_mfma_f32_32x32x16_bf16(af.v, b1_, acc1, 0, 0, 0); \
    }
#define QSTEP4(S)  QSTEP(S) QSTEP((S)+1) QSTEP((S)+2) QSTEP((S)+3)
#define QSTEP16(S) QSTEP4(S) QSTEP4((S)+4) QSTEP4((S)+8) QSTEP4((S)+12)
        QSTEP16(0) QSTEP16(16) QSTEP16(32) QSTEP16(48)
#undef QSTEP16
#undef QSTEP4
#undef QSTEP

        // ---- 2 linear tail steps (p = u): af IS the packed u slice ----
#define TSTEP(S) { \
        constexpr int sl_ = (S) * 4; \
        AF af; \
        af.w[0] = v2_pk[sl_ + 0]; \
        af.w[1] = v2_pk[sl_ + 1]; \
        af.w[2] = v2_pk[sl_ + 2]; \
        af.w[3] = v2_pk[sl_ + 3]; \
        const bf16x8 b0_ = *(const bf16x8*)((const char*)Wl + toff0[S]); \
        const bf16x8 b1_ = *(const bf16x8*)((const char*)Wl + toff1[S]); \
        acc0 = __builtin_amdgcn_mfma_f32_32x32x16_bf16(af.v, b0_, acc0, 0, 0, 0); \
        acc1 = __builtin_amdgcn_mfma_f32_32x32x16_bf16(af.v, b1_, acc1, 0, 0, 0); \
    }
        TSTEP(0) TSTEP(1)
#undef TSTEP

        // ---- C store, straight-line: row(reg)=(reg&3)+8*(reg>>2)+4*half ----
        float* bo = Bu + (size_t)base * D_H;
        const int r4 = 4 * half;
#define CSTORE(RG) { \
        constexpr int rg_ = (RG); \
        constexpr int r0_ = (rg_ & 3) + 8 * (rg_ >> 2); \
        bo[(size_t)(r0_ + r4) * D_H + colr]      = acc0[rg_]; \
        bo[(size_t)(r0_ + r4) * D_H + 32 + colr] = acc1[rg_]; \
    }
#define CSTORE4(S) CSTORE(S) CSTORE((S)+1) CSTORE((S)+2) CSTORE((S)+3)
        CSTORE4(0) CSTORE4(4) CSTORE4(8) CSTORE4(12)
#undef CSTORE4
#undef CSTORE
    }
}

// ---------------- Phase 2: chunked scan, one block per batch row ----------
// 8 waves = 8 chunks of 128 steps. Pass 1: per-chunk affine (P,Q) with Bu
// (f32) packed to bf16 pairs parked in 64 VGPRs. Block scan via LDS. Pass 2:
// replay from regs.
#define NCH 8
#define CLEN 128
__global__ __launch_bounds__(512) void im_scan(
    const float* __restrict__ h0, const int* __restrict__ int_lens,
    const float* __restrict__ A_log,
    const float* __restrict__ Bu, const float* __restrict__ xbuf,
    float* __restrict__ out)
{
    __shared__ float Pl[NCH][64], Ql[NCH][64];
    const int b = blockIdx.x;
    const int wave = threadIdx.x >> 6;
    const int lane = threadIdx.x & 63;
    const int k0 = wave * CLEN;

    float A = -__expf(A_log[lane]);
    float invA = 1.f / A;
    int len = int_lens[b];

    float xv0 = xbuf[(size_t)b * K_SZ + k0 + lane];
    float xv1 = xbuf[(size_t)b * K_SZ + k0 + 64 + lane];
    const float* bup = Bu + ((size_t)(b * K_SZ + k0)) * D_H + lane;

    uint32_t bu[64];
    float P = 1.f, Q = 0.f;
    #pragma unroll
    for (int s2 = 0; s2 < 64; ++s2) {
        float lo = bup[(size_t)(2 * s2) * D_H];
        float hi = bup[(size_t)(2 * s2 + 1) * D_H];
        bu[s2] = pack_bf16_trunc(lo, hi);
        {
            const int t = 2 * s2;
            float x = (t < 64) ? rdlane(xv0, t & 63) : rdlane(xv1, t & 63);
            float eA = __expf(A * x);
            bool act = (k0 + t) < len;
            float Pf = act ? eA : 1.f;
            float cf = act ? (eA - 1.f) * invA * lo : 0.f;
            P *= Pf;
            Q = fmaf(Pf, Q, cf);
        }
        {
            const int t = 2 * s2 + 1;
            float x = (t < 64) ? rdlane(xv0, t & 63) : rdlane(xv1, t & 63);
            float eA = __expf(A * x);
            bool act = (k0 + t) < len;
            float Pf = act ? eA : 1.f;
            float cf = act ? (eA - 1.f) * invA * hi : 0.f;
            P *= Pf;
            Q = fmaf(Pf, Q, cf);
        }
    }
    Pl[wave][lane] = P;
    Ql[wave][lane] = Q;
    __syncthreads();

    // chunk start state
    float hv = h0[b * D_H + lane];
    for (int cc = 0; cc < wave; ++cc)
        hv = fmaf(Pl[cc][lane], hv, Ql[cc][lane]);

    float* times  = out + (size_t)B_SZ * D_H;
    float* states = times + (size_t)(K_SZ + 1) * B_SZ;
    if (wave == 0)
        states[(size_t)b * D_H + lane] = hv;   // states[0] = h0

    // replay from registers (Bu truncated to bf16 in-reg)
    #pragma unroll
    for (int s2 = 0; s2 < 64; ++s2) {
        uint32_t w = bu[s2];
        {
            const int t = 2 * s2;
            float Buf = __builtin_bit_cast(float, w << 16);
            float x = (t < 64) ? rdlane(xv0, t & 63) : rdlane(xv1, t & 63);
            float eA = __expf(A * x);
            float hn = fmaf(eA, hv, (eA - 1.f) * invA * Buf);
            hv = ((k0 + t) < len) ? hn : hv;
            states[((size_t)(k0 + t + 1) * B_SZ + b) * D_H + lane] = hv;
        }
        {
            const int t = 2 * s2 + 1;
            float Buf = __builtin_bit_cast(float, w & 0xFFFF0000u);
            float x = (t < 64) ? rdlane(xv0, t & 63) : rdlane(xv1, t & 63);
            float eA = __expf(A * x);
            float hn = fmaf(eA, hv, (eA - 1.f) * invA * Buf);
            hv = ((k0 + t) < len) ? hn : hv;
            states[((size_t)(k0 + t + 1) * B_SZ + b) * D_H + lane] = hv;
        }
    }
    if (wave == NCH - 1)
        out[b * D_H + lane] = hv;   // h_final
}

// ---------------- times: (K+1, B) transpose of t_int ----------------------
__global__ __launch_bounds__(256) void im_times(
    const float* __restrict__ t_int, float* __restrict__ out)
{
    int idx = blockIdx.x * blockDim.x + threadIdx.x;
    if (idx >= (K_SZ + 1) * B_SZ) return;
    int kp = idx >> 9;            // / B_SZ
    int b  = idx & (B_SZ - 1);
    int ks = (kp == 0) ? 0 : kp - 1;
    float* times = out + (size_t)B_SZ * D_H;
    times[idx] = t_int[(size_t)b * K_SZ + ks];
}

extern "C" void kernel_launch(void* const* d_in, const int* in_sizes, int n_in,
                              void* d_out, int out_size, void* d_ws, size_t ws_size,
                              hipStream_t stream) {
    const float* h0       = (const float*)d_in[0];
    const float* t_int    = (const float*)d_in[1];
    const float* U_int    = (const float*)d_in[2];
    const int*   int_lens = (const int*)d_in[3];
    const float* Wp       = (const float*)d_in[4];
    const float* bp       = (const float*)d_in[5];
    const float* gamma    = (const float*)d_in[6];
    const float* beta     = (const float*)d_in[7];
    const float* A_log    = (const float*)d_in[8];
    const float* Bmat     = (const float*)d_in[9];
    const float* Ws       = (const float*)d_in[10];
    const float* bs       = (const float*)d_in[11];

    float* out = (float*)d_out;
    float* Bu   = (float*)d_ws;                                    // B*K*D_H f32
    float* xbuf = (float*)((char*)d_ws + (size_t)B_SZ * K_SZ * D_H * sizeof(float));

    size_t lds_bytes = (size_t)D_H * KPL * sizeof(uint16_t);   // 139264
    im_phase1<<<dim3(P1_BLOCKS), dim3(P1_THREADS), lds_bytes, stream>>>(
        t_int, U_int, Wp, bp, gamma, beta, Bmat, Ws, bs, Bu, xbuf);

    im_times<<<dim3(((K_SZ + 1) * B_SZ + 255) / 256), dim3(256), 0, stream>>>(t_int, out);

    im_scan<<<dim3(B_SZ), dim3(512), 0, stream>>>(h0, int_lens, A_log, Bu, xbuf, out);
}